// Round 5
// baseline (1318.467 us; speedup 1.0000x reference)
//
#include <hip/hip_runtime.h>

#define NN 50000
#define NP 50048   // padded rows for global_load_lds tail reads
#define NMT64 782  // cdiv(NN,64)
#define NMT32 1563 // cdiv(NN,32)
#define NE 800000
#define EP (NE + NN)
#define DEMB 128
#define DHID 512
#define NB_SCAN 196  // cdiv(NN,256)

typedef unsigned short ushort_t;
typedef __attribute__((ext_vector_type(8))) short short8_t;
typedef __attribute__((ext_vector_type(4))) float float4_t;

__device__ __forceinline__ float bf2f(ushort_t u) {
    return __uint_as_float(((unsigned int)u) << 16);
}
__device__ __forceinline__ ushort_t f2bf(float f) {
    unsigned int x = __float_as_uint(f);
    x += 0x7fffu + ((x >> 16) & 1u);
    return (ushort_t)(x >> 16);
}
__device__ __forceinline__ float lo16(unsigned int w) { return __uint_as_float(w << 16); }
__device__ __forceinline__ float hi16(unsigned int w) { return __uint_as_float(w & 0xffff0000u); }
__device__ __forceinline__ unsigned int pack2(float a, float b) {
    return (unsigned int)f2bf(a) | ((unsigned int)f2bf(b) << 16);
}
__device__ __forceinline__ void gl_lds16(const ushort_t* g, ushort_t* l) {
    __builtin_amdgcn_global_load_lds(
        (const __attribute__((address_space(1))) void*)g,
        (__attribute__((address_space(3))) void*)l, 16, 0, 0);
}
static inline int cdiv(int a, int b) { return (a + b - 1) / b; }

// ---------------- dtype detect + batched convert ----------------
__global__ void k_detect(const unsigned int* __restrict__ Jw, int* __restrict__ flag) {
    if (threadIdx.x != 0 || blockIdx.x != 0) return;
    int votes = 0;
    for (int i = 0; i < 8; ++i) {
        unsigned int w = Jw[i];
        unsigned int ex = (w >> 23) & 0xFFu;
        if ((w >> 31) == 0u && ex >= 100u && ex <= 126u) votes++;
    }
    *flag = (votes >= 6) ? 1 : 0;
}

struct CvtArgs {
    const void* src[16];
    float* dst[16];
    int n[16];
};
__global__ void k_cvt_all(CvtArgs a, const int* __restrict__ flag) {
    int which = blockIdx.y;
    int i = blockIdx.x * 256 + threadIdx.x;
    if (i >= a.n[which]) return;
    float v;
    if (*flag) v = ((const float*)a.src[which])[i];
    else       v = bf2f(((const ushort_t*)a.src[which])[i]);
    a.dst[which][i] = v;
}

struct TrArgs {
    const float* src[6];
    ushort_t* dst[6];
    int K[6];
    int Nc[6];
    int perm[6];
};
// plain [K][Nc] -> [Nc][K] transpose to bf16 (perm unused: BM=32 k_ffn H-packing
// pairs consecutive hid cols, so the W3 k-permutation is the identity).
__global__ void k_tr_all(TrArgs a) {
    int which = blockIdx.y;
    int idx = blockIdx.x * 256 + threadIdx.x;
    int K = a.K[which], Nc = a.Nc[which];
    if (idx >= K * Nc) return;
    int k = idx / Nc, n = idx - k * Nc;
    a.dst[which][n * K + k] = f2bf(a.src[which][idx]);
}

// ---------------- CSR build ----------------
__global__ void k_deg(const int* __restrict__ ei, int* __restrict__ deg) {
    int e = blockIdx.x * 256 + threadIdx.x;
    if (e >= EP) return;
    int d = (e < NE) ? ei[NE + e] : (e - NE);
    atomicAdd(&deg[d], 1);
}

__global__ void k_part(const int* __restrict__ deg, int* __restrict__ part) {
    __shared__ int sm[256];
    int i = blockIdx.x * 256 + threadIdx.x;
    int v = (i < NN) ? deg[i] : 0;
    sm[threadIdx.x] = v;
    __syncthreads();
    for (int off = 128; off > 0; off >>= 1) {
        if (threadIdx.x < off) sm[threadIdx.x] += sm[threadIdx.x + off];
        __syncthreads();
    }
    if (threadIdx.x == 0) part[blockIdx.x] = sm[0];
}

__global__ void k_scan2(const int* __restrict__ part, int* __restrict__ poff,
                        int* __restrict__ rowp) {
    __shared__ int sm[256];
    int t = threadIdx.x;
    int v = (t < NB_SCAN) ? part[t] : 0;
    sm[t] = v;
    __syncthreads();
    int incl = v;
    for (int off = 1; off < 256; off <<= 1) {
        int u = (t >= off) ? sm[t - off] : 0;
        __syncthreads();
        incl += u;
        sm[t] = incl;
        __syncthreads();
    }
    if (t < NB_SCAN) poff[t] = incl - v;
    if (t == 255) rowp[NN] = sm[255];
}

// rowp + dinv + fill-init fused
__global__ void k_rowp(const int* __restrict__ deg, const int* __restrict__ poff,
                       int* __restrict__ rowp, float* __restrict__ dinv,
                       int* __restrict__ fill) {
    __shared__ int sm[256];
    int i = blockIdx.x * 256 + threadIdx.x;
    int t = threadIdx.x;
    int v = (i < NN) ? deg[i] : 0;
    sm[t] = v;
    __syncthreads();
    int incl = v;
    for (int off = 1; off < 256; off <<= 1) {
        int u = (t >= off) ? sm[t - off] : 0;
        __syncthreads();
        incl += u;
        sm[t] = incl;
        __syncthreads();
    }
    if (i < NN) {
        int rp = poff[blockIdx.x] + incl - v;
        rowp[i] = rp;
        fill[i] = rp;
        dinv[i] = rsqrtf(fmaxf((float)v, 1.0f));
    }
}

__global__ void k_fill(const int* __restrict__ ei, int* __restrict__ fillpos,
                       ushort_t* __restrict__ col) {
    int e = blockIdx.x * 256 + threadIdx.x;
    if (e >= EP) return;
    int s, d;
    if (e < NE) { s = ei[e]; d = ei[NE + e]; } else { s = d = e - NE; }
    int pos = atomicAdd(&fillpos[d], 1);
    col[pos] = (ushort_t)s;
}

// ---------------- elementwise ----------------
__global__ void k_lin0(const float* __restrict__ x, const float* __restrict__ J,
                       const float* __restrict__ w, const float* __restrict__ b,
                       ushort_t* __restrict__ hB) {
    int idx = blockIdx.x * 256 + threadIdx.x;
    if (idx >= NN * DEMB) return;
    int n = idx >> 7, d = idx & 127;
    float v = x[n * 2] * w[d] + x[n * 2 + 1] * w[DEMB + d] + J[n] * w[2 * DEMB + d] + b[d];
    hB[idx] = f2bf(v);
}

__global__ void k_att(const unsigned int* __restrict__ xlB, const float* __restrict__ asrc,
                      const float* __restrict__ adst, float* __restrict__ a_s,
                      float* __restrict__ a_d) {
    int idx = blockIdx.x * 256 + threadIdx.x;
    if (idx >= NN * 8) return;
    int n = idx >> 3, hh = idx & 7;
    const unsigned int* row = xlB + (size_t)n * 64 + hh * 8;
    float s = 0.f, d = 0.f;
#pragma unroll
    for (int c = 0; c < 8; ++c) {
        unsigned int w = row[c];
        float v0 = lo16(w), v1 = hi16(w);
        s += v0 * asrc[hh * 16 + 2 * c] + v1 * asrc[hh * 16 + 2 * c + 1];
        d += v0 * adst[hh * 16 + 2 * c] + v1 * adst[hh * 16 + 2 * c + 1];
    }
    a_s[idx] = s;
    a_d[idx] = d;
}

// BN1 stats pass: recompute z = h + g@w1 (h from bf16), accumulate stats only
__global__ __launch_bounds__(256) void k_z1s(const ushort_t* __restrict__ hB,
                                             const float* __restrict__ g,
                                             const float* __restrict__ w1,
                                             float* __restrict__ stats) {
    int d = threadIdx.x & 127;
    int rstart = blockIdx.x * 2 + (threadIdx.x >> 7);
    int stride = gridDim.x * 2;
    float s1 = 0.f, s2 = 0.f;
    for (int r = rstart; r < NN; r += stride) {
        const float* gr = g + r * 16;
        float s = bf2f(hB[(size_t)r * DEMB + d]);
#pragma unroll
        for (int c = 0; c < 16; ++c) s += gr[c] * w1[c * DEMB + d];
        s1 += s;
        s2 += s * s;
    }
    __shared__ float b1[256], b2[256];
    b1[threadIdx.x] = s1;
    b2[threadIdx.x] = s2;
    __syncthreads();
    if (threadIdx.x < 128) {
        atomicAdd(&stats[threadIdx.x], b1[threadIdx.x] + b1[threadIdx.x + 128]);
        atomicAdd(&stats[128 + threadIdx.x], b2[threadIdx.x] + b2[threadIdx.x + 128]);
    }
}

// BN1 apply with recompute (h from bf16); out h1 bf16 only
__global__ void k_bnapply1(const ushort_t* __restrict__ hB, const float* __restrict__ g,
                           const float* __restrict__ w1, const float* __restrict__ stats,
                           const float* __restrict__ gam, const float* __restrict__ bet,
                           ushort_t* __restrict__ outB) {
    int idx = blockIdx.x * 256 + threadIdx.x;
    if (idx >= NN * DEMB) return;
    int n = idx >> 7, d = idx & 127;
    float s = bf2f(hB[idx]);
    const float* gr = g + n * 16;
#pragma unroll
    for (int c = 0; c < 16; ++c) s += gr[c] * w1[c * DEMB + d];
    const float invN = 1.0f / (float)NN;
    float mu = stats[d] * invN;
    float var = stats[128 + d] * invN - mu * mu;
    float rs = rsqrtf(fmaxf(var, 0.f) + 1e-5f);
    float v = gam[d] * (s - mu) * rs + bet[d];
    outB[idx] = f2bf(v);
}

// BN2 apply (layer 0): z from bf16; out hB bf16
__global__ void k_bnapply(const ushort_t* __restrict__ zB, const float* __restrict__ stats,
                          const float* __restrict__ gam, const float* __restrict__ bet,
                          ushort_t* __restrict__ outB) {
    int idx = blockIdx.x * 256 + threadIdx.x;
    if (idx >= NN * DEMB) return;
    int d = idx & 127;
    const float invN = 1.0f / (float)NN;
    float mu = stats[d] * invN;
    float var = stats[128 + d] * invN - mu * mu;
    float rs = rsqrtf(fmaxf(var, 0.f) + 1e-5f);
    float v = gam[d] * (bf2f(zB[idx]) - mu) * rs + bet[d];
    outB[idx] = f2bf(v);
}

// BN2 apply (layer 1, final): z from bf16; emit APPNP inputs in SLAB-MAJOR
// layout [4 slabs][NN][16 u32] (slab q = dims [32q,32q+32))
__global__ void k_bnapply_fin(const unsigned int* __restrict__ zB, const float* __restrict__ stats,
                              const float* __restrict__ gam, const float* __restrict__ bet,
                              const float* __restrict__ dinv,
                              unsigned int* __restrict__ hs, unsigned int* __restrict__ h0p) {
    int idx = blockIdx.x * 256 + threadIdx.x;
    if (idx >= NN * 64) return;
    int n = idx >> 6, j = idx & 63;
    int d0 = j * 2;
    const float invN = 1.0f / (float)NN;
    unsigned int zw = zB[idx];
    float z0 = lo16(zw), z1 = hi16(zw);
    float mu0 = stats[d0] * invN, mu1 = stats[d0 + 1] * invN;
    float v0 = stats[128 + d0] * invN - mu0 * mu0;
    float v1 = stats[128 + d0 + 1] * invN - mu1 * mu1;
    float rs0 = rsqrtf(fmaxf(v0, 0.f) + 1e-5f);
    float rs1 = rsqrtf(fmaxf(v1, 0.f) + 1e-5f);
    float a = gam[d0] * (z0 - mu0) * rs0 + bet[d0];
    float b = gam[d0 + 1] * (z1 - mu1) * rs1 + bet[d0 + 1];
    float di = dinv[n];
    int q = j >> 4, dd = j & 15;
    size_t o = (size_t)q * NN * 16 + (size_t)n * 16 + dd;
    hs[o] = pack2(di * a, di * b);
    h0p[o] = pack2(a, b);
}

// ---------------- GAT: single-pass softmax-aggregate (wave per node) ----------------
__global__ __launch_bounds__(256) void k_gat(const int* __restrict__ rowp,
                                             const ushort_t* __restrict__ col,
                                             const float* __restrict__ a_s, const float* __restrict__ a_d,
                                             const unsigned int* __restrict__ xlB, float* __restrict__ g) {
    int wid = (blockIdx.x * 256 + threadIdx.x) >> 6;
    int lane = threadIdx.x & 63;
    if (wid >= NN) return;
    int p0 = rowp[wid], p1 = rowp[wid + 1];
    int hh = lane >> 3;
    float ad2 = a_d[wid * 8 + hh];
    float acc0 = 0.f, acc1 = 0.f, s = 0.f;
    int p = p0;
    while (p < p1) {
        int cnt = p1 - p;
        if (cnt > 64) cnt = 64;
        int pl = p + lane;
        int jv = (int)col[pl < p1 ? pl : (p1 - 1)];
        int i = 0;
        for (; i + 8 <= cnt; i += 8) {
            int j0 = __shfl(jv, i),     j1 = __shfl(jv, i + 1);
            int j2 = __shfl(jv, i + 2), j3 = __shfl(jv, i + 3);
            int j4 = __shfl(jv, i + 4), j5 = __shfl(jv, i + 5);
            int j6 = __shfl(jv, i + 6), j7 = __shfl(jv, i + 7);
            float e0 = a_s[j0 * 8 + hh] + ad2, e1 = a_s[j1 * 8 + hh] + ad2;
            float e2 = a_s[j2 * 8 + hh] + ad2, e3 = a_s[j3 * 8 + hh] + ad2;
            float e4 = a_s[j4 * 8 + hh] + ad2, e5 = a_s[j5 * 8 + hh] + ad2;
            float e6 = a_s[j6 * 8 + hh] + ad2, e7 = a_s[j7 * 8 + hh] + ad2;
            unsigned int w0 = xlB[j0 * 64 + lane], w1 = xlB[j1 * 64 + lane];
            unsigned int w2 = xlB[j2 * 64 + lane], w3 = xlB[j3 * 64 + lane];
            unsigned int w4 = xlB[j4 * 64 + lane], w5 = xlB[j5 * 64 + lane];
            unsigned int w6 = xlB[j6 * 64 + lane], w7 = xlB[j7 * 64 + lane];
            e0 = e0 > 0.f ? e0 : 0.2f * e0;  e1 = e1 > 0.f ? e1 : 0.2f * e1;
            e2 = e2 > 0.f ? e2 : 0.2f * e2;  e3 = e3 > 0.f ? e3 : 0.2f * e3;
            e4 = e4 > 0.f ? e4 : 0.2f * e4;  e5 = e5 > 0.f ? e5 : 0.2f * e5;
            e6 = e6 > 0.f ? e6 : 0.2f * e6;  e7 = e7 > 0.f ? e7 : 0.2f * e7;
            float al0 = __expf(e0), al1 = __expf(e1), al2 = __expf(e2), al3 = __expf(e3);
            float al4 = __expf(e4), al5 = __expf(e5), al6 = __expf(e6), al7 = __expf(e7);
            s += al0 + al1 + al2 + al3 + al4 + al5 + al6 + al7;
            acc0 += al0 * lo16(w0) + al1 * lo16(w1) + al2 * lo16(w2) + al3 * lo16(w3) +
                    al4 * lo16(w4) + al5 * lo16(w5) + al6 * lo16(w6) + al7 * lo16(w7);
            acc1 += al0 * hi16(w0) + al1 * hi16(w1) + al2 * hi16(w2) + al3 * hi16(w3) +
                    al4 * hi16(w4) + al5 * hi16(w5) + al6 * hi16(w6) + al7 * hi16(w7);
        }
        for (; i < cnt; ++i) {
            int j = __shfl(jv, i);
            float e = a_s[j * 8 + hh] + ad2;
            e = e > 0.f ? e : 0.2f * e;
            float al = __expf(e);
            unsigned int w = xlB[j * 64 + lane];
            s += al;
            acc0 += al * lo16(w);
            acc1 += al * hi16(w);
        }
        p += cnt;
    }
    float inv = 1.f / s;
    acc0 *= inv;
    acc1 *= inv;
    acc0 += __shfl_xor(acc0, 8);  acc1 += __shfl_xor(acc1, 8);
    acc0 += __shfl_xor(acc0, 16); acc1 += __shfl_xor(acc1, 16);
    acc0 += __shfl_xor(acc0, 32); acc1 += __shfl_xor(acc1, 32);
    if (lane < 8) ((float2*)g)[wid * 8 + lane] = make_float2(acc0, acc1);
}

// ---------------- APPNP step: dimension-slabbed gather ----------------
// hs/h0p layout [4 slabs][NN][16 u32]; slab q holds dims [32q,32q+32).
// Wave = 1 node x 1 slab: 64 lanes = 4 edge-slots x 16 dims. Per 4 edges, one
// wave-load covers 4x64B segments. Block->slab map (b&7)>>1 rides the XCD
// round-robin: each XCD touches ONE 3.2MB slab -> L2-resident gather (vs 12.8MB
// working set refetched by all 8 XCDs: FETCH 90.8 MB/step in round 4).
__global__ __launch_bounds__(256) void k_appnp(const int* __restrict__ rowp,
                                               const ushort_t* __restrict__ col,
                                               const float* __restrict__ dinv,
                                               const unsigned int* __restrict__ hs,
                                               const unsigned int* __restrict__ h0p,
                                               unsigned int* __restrict__ hs_out,
                                               const float* __restrict__ Jf,
                                               const int* __restrict__ flag,
                                               void* __restrict__ out, int writeOut) {
    int b = blockIdx.x;
    int w = threadIdx.x >> 6, lane = threadIdx.x & 63;
    int s = (b & 7) >> 1;                 // slab (2 XCDs per slab)
    int i = ((b >> 3) << 1) + (b & 1);    // within-slab node-group [0,12500)
    int n = i * 4 + w;                    // node (< 50000 exactly)
    int es = lane >> 4, d = lane & 15;
    int p0 = rowp[n], p1 = rowp[n + 1];
    const unsigned int* hsq = hs + (size_t)s * NN * 16;
    float a0 = 0.f, a1 = 0.f;
    int p = p0;
    for (; p + 8 <= p1; p += 8) {
        int j0 = (int)col[p + es];
        int j1 = (int)col[p + 4 + es];
        unsigned int w0 = hsq[j0 * 16 + d];
        unsigned int w1 = hsq[j1 * 16 + d];
        a0 += lo16(w0) + lo16(w1);
        a1 += hi16(w0) + hi16(w1);
    }
    for (; p < p1; p += 4) {
        int pe = p + es;
        int j = (int)col[pe < p1 ? pe : (p1 - 1)];
        unsigned int wv = hsq[j * 16 + d];
        if (pe < p1) { a0 += lo16(wv); a1 += hi16(wv); }
    }
    a0 += __shfl_xor(a0, 16); a1 += __shfl_xor(a1, 16);
    a0 += __shfl_xor(a0, 32); a1 += __shfl_xor(a1, 32);
    float di = dinv[n];
    unsigned int hw = h0p[(size_t)s * NN * 16 + (size_t)n * 16 + d];
    float n0 = 0.9f * di * a0 + 0.1f * lo16(hw);
    float n1 = 0.9f * di * a1 + 0.1f * hi16(hw);
    if (!writeOut) {
        if (es == 0)
            hs_out[(size_t)s * NN * 16 + (size_t)n * 16 + d] = pack2(di * n0, di * n1);
    } else if (es == 0) {
        size_t base = (size_t)n * 129 + s * 32 + 2 * d;
        if (*flag) {
            float* o = (float*)out;
            o[base] = n0;
            o[base + 1] = n1;
            if (s == 0 && d == 0) o[(size_t)n * 129 + 128] = Jf[n];
        } else {
            ushort_t* o = (ushort_t*)out;
            o[base] = f2bf(n0);
            o[base + 1] = f2bf(n1);
            if (s == 0 && d == 0) o[(size_t)n * 129 + 128] = f2bf(Jf[n]);
        }
    }
}

// ---------------- 64x128-tile MFMA GEMM, double-buffered ----------
// MODE 3: outB = bf16(acc)   (used for xl = h @ gat_w)
template <int MODE>
__global__ __launch_bounds__(256) void k_gemm64(const ushort_t* __restrict__ A,
                                                const ushort_t* __restrict__ Bt,
                                                int M, int K, int Nc,
                                                const float* __restrict__ bias,
                                                const ushort_t* __restrict__ res,
                                                ushort_t* __restrict__ outB,
                                                float* __restrict__ stats) {
    __shared__ __align__(16) ushort_t lsA[2][64 * 32];
    __shared__ __align__(16) ushort_t lsB[2][128 * 32];
    int t = threadIdx.x;
    int m0 = blockIdx.x * 64;
    int n0 = blockIdx.y * 128;
    int w = t >> 6, lane = t & 63;
    int row16 = lane & 15, quad = lane >> 4;
    int nbase = w * 32;
    float4_t acc[8];
#pragma unroll
    for (int i = 0; i < 8; ++i) acc[i] = (float4_t){0.f, 0.f, 0.f, 0.f};
    int lrow = lane >> 2;
    int lcol = (lane & 3) * 8;
    const ushort_t* gA  = A  + (size_t)(m0 + w * 16 + lrow) * K + lcol;
    const ushort_t* gB0 = Bt + (size_t)(n0 + w * 32 + lrow) * K + lcol;
    const ushort_t* gB1 = Bt + (size_t)(n0 + w * 32 + 16 + lrow) * K + lcol;
    ushort_t* dA  = &lsA[0][0] + (w * 16) * 32;
    ushort_t* dB0 = &lsB[0][0] + (w * 32) * 32;
    ushort_t* dB1 = &lsB[0][0] + (w * 32 + 16) * 32;
    const int bufStrideA = 64 * 32, bufStrideB = 128 * 32;
    const int nK = K >> 5;
    gl_lds16(gA, dA);
    gl_lds16(gB0, dB0);
    gl_lds16(gB1, dB1);
    for (int kb = 0; kb < nK; ++kb) {
        __syncthreads();
        int nb = kb + 1;
        if (nb < nK) {
            int b = nb & 1;
            int k0 = nb << 5;
            gl_lds16(gA + k0, dA + b * bufStrideA);
            gl_lds16(gB0 + k0, dB0 + b * bufStrideB);
            gl_lds16(gB1 + k0, dB1 + b * bufStrideB);
        }
        const ushort_t* la = &lsA[kb & 1][0];
        const ushort_t* lb = &lsB[kb & 1][0];
        short8_t afr[4], bfr[2];
#pragma unroll
        for (int i = 0; i < 4; ++i)
            afr[i] = *(const short8_t*)(la + (i * 16 + row16) * 32 + quad * 8);
#pragma unroll
        for (int i = 0; i < 2; ++i)
            bfr[i] = *(const short8_t*)(lb + (nbase + i * 16 + row16) * 32 + quad * 8);
#pragma unroll
        for (int mt = 0; mt < 4; ++mt)
#pragma unroll
            for (int nt = 0; nt < 2; ++nt)
                acc[mt * 2 + nt] = __builtin_amdgcn_mfma_f32_16x16x32_bf16(
                    afr[mt], bfr[nt], acc[mt * 2 + nt], 0, 0, 0);
    }
#pragma unroll
    for (int mt = 0; mt < 4; ++mt) {
#pragma unroll
        for (int nt = 0; nt < 2; ++nt) {
            int cc = n0 + nbase + nt * 16 + row16;
#pragma unroll
            for (int r = 0; r < 4; ++r) {
                int rr = m0 + mt * 16 + quad * 4 + r;
                if (rr < M) {
                    outB[(size_t)rr * Nc + cc] = f2bf(acc[mt * 2 + nt][r]);
                }
            }
        }
    }
}

// ---------------- fused FFN, BM=32: z = relu(A@W2+b2)@W3 + b3 + res, + BN stats ----
// A:[NP][128] bf16, W2t:[512 n][128 k] bf16, W3t:[128 n][512 k] bf16 (plain).
// 1563 blocks (~6.1/CU), LDS = 16K(W2) + 16K(W3) + 8K(A prologue -> H 4K + stats 1K)
// = 40KB -> 4 blocks/CU, 16 waves/CU. Per-block critical path halved vs BM=64
// (8+8 MFMA, ~12 LDS reads per wave per chunk). Waves split 4-way in n.
// Two barriers/chunk with staggered single-buffer restaging (stage after the
// barrier that retires the previous consumer; drained by the NEXT barrier's
// vmcnt(0), one full phase later).
// H tile 32x128B: u32 kidx holds hid cols (2kidx, 2kidx+1) - consecutive pairing
// -> afrH delivers canonical k order -> NO W3 k-permutation. Lane packs its col
// with its neighbor's via __shfl_xor(v,1); 16B slots XOR-swizzled by (row&7).
__global__ __launch_bounds__(256, 4) void k_ffn(const ushort_t* __restrict__ A,
                                                const ushort_t* __restrict__ W2t,
                                                const ushort_t* __restrict__ W3t,
                                                const float* __restrict__ b2,
                                                const float* __restrict__ b3,
                                                const ushort_t* __restrict__ res,
                                                ushort_t* __restrict__ outB,
                                                float* __restrict__ stats) {
    __shared__ __align__(16) ushort_t sW2[4 * 64 * 32];   // 16KB [kb][64 n][32 k]
    __shared__ __align__(16) ushort_t sW3[2 * 128 * 32];  // 16KB [ks][128 n][32 k]
    __shared__ __align__(16) ushort_t sAH[4 * 1024];      // 8KB A prologue [kb][32 r][32 k]; then H+stats
    int t = threadIdx.x;
    int w = t >> 6, lane = t & 63;       // w = n-quarter
    int m0 = blockIdx.x * 32;
    int row16 = lane & 15, quad = lane >> 4;
    int sw = (row16 >> 2) & 3;   // read-side k-group swizzle
    int srow = lane >> 2;        // staging: row within a 16-row issue
    int klin = lane & 3;         // staging: linear k-group this lane fills

    // ---- prologue staging: A tile (wave w -> kb=w), W2 chunk 0, W3 chunk 0 ----
#pragma unroll
    for (int i = 0; i < 2; ++i) {
        int row = i * 16 + srow;
        int kc = klin ^ ((row >> 2) & 3);
        gl_lds16(A + (size_t)(m0 + row) * 128 + w * 32 + kc * 8,
                 sAH + w * 1024 + i * 512);
    }
#pragma unroll
    for (int i = 0; i < 4; ++i) {
        int n = i * 16 + srow;
        int kc = klin ^ ((n >> 2) & 3);
        gl_lds16(W2t + (size_t)n * 128 + w * 32 + kc * 8,
                 sW2 + w * 2048 + i * 512);
        int f = w * 4 + i;
        int ks = f >> 3;
        int n3 = (f & 7) * 16 + srow;
        int kc3 = klin ^ ((n3 >> 2) & 3);
        gl_lds16(W3t + (size_t)n3 * 512 + ks * 32 + kc3 * 8,
                 sW3 + f * 512);
    }
    __syncthreads();

    // hoist A fragments (chunk-invariant): afrA[mt][kb], 32 VGPRs
    short8_t afrA[2][4];
#pragma unroll
    for (int mt = 0; mt < 2; ++mt)
#pragma unroll
        for (int kb = 0; kb < 4; ++kb)
            afrA[mt][kb] = *(const short8_t*)(sAH + kb * 1024 +
                                              (mt * 16 + row16) * 32 + (quad ^ sw) * 8);
    __syncthreads();   // A region free -> H + stats

    char* Hb = (char*)sAH;             // 4KB H: 32 rows x 128B
    float* s1 = (float*)(Hb + 4096);   // 128 f32
    float* s2 = s1 + 128;
    if (t < 128) { s1[t] = 0.f; s2[t] = 0.f; }

    float4_t accz[2][2];
#pragma unroll
    for (int mt = 0; mt < 2; ++mt)
#pragma unroll
        for (int nt = 0; nt < 2; ++nt) accz[mt][nt] = (float4_t){0.f, 0.f, 0.f, 0.f};

    for (int c = 0; c < 8; ++c) {
        // ---- phase 1: hid_c = relu(A @ W2[:, 64c:64c+64] + b2), 16-col slice w ----
        float b2v = b2[c * 64 + w * 16 + row16];
        float4_t acch[2];
        acch[0] = (float4_t){0.f, 0.f, 0.f, 0.f};
        acch[1] = (float4_t){0.f, 0.f, 0.f, 0.f};
#pragma unroll
        for (int kb = 0; kb < 4; ++kb) {
            short8_t b0 = *(const short8_t*)(sW2 + kb * 2048 +
                                             (w * 16 + row16) * 32 + (quad ^ sw) * 8);
            acch[0] = __builtin_amdgcn_mfma_f32_16x16x32_bf16(afrA[0][kb], b0, acch[0], 0, 0, 0);
            acch[1] = __builtin_amdgcn_mfma_f32_16x16x32_bf16(afrA[1][kb], b0, acch[1], 0, 0, 0);
        }
        // relu+bias -> packed H (pair col with col^1 via shfl; even lanes write b32)
#pragma unroll
        for (int mt = 0; mt < 2; ++mt) {
#pragma unroll
            for (int r = 0; r < 4; ++r) {
                int row = mt * 16 + quad * 4 + r;
                float v = acch[mt][r] + b2v;
                v = v > 0.f ? v : 0.f;
                float vo = __shfl_xor(v, 1);
                if (!(row16 & 1)) {
                    int kidx = w * 8 + (row16 >> 1);
                    int byteOff = row * 128 + ((((kidx >> 2) ^ (row & 7))) << 4) + (kidx & 3) * 4;
                    *(unsigned int*)(Hb + byteOff) = pack2(v, vo);
                }
            }
        }
        __syncthreads();   // B1: H visible; W2(c) fully consumed
        if (c < 7) {       // restage W2 (drained by vmcnt(0) at B2)
#pragma unroll
            for (int i = 0; i < 4; ++i) {
                int n = i * 16 + srow;
                int kc = klin ^ ((n >> 2) & 3);
                gl_lds16(W2t + (size_t)((c + 1) * 64 + n) * 128 + w * 32 + kc * 8,
                         sW2 + w * 2048 + i * 512);
            }
        }
        // ---- phase 2: accz += hid_c @ W3[64c:64c+64, :], 32-col slice w ----
#pragma unroll
        for (int ks = 0; ks < 2; ++ks) {
            short8_t afrH[2];
#pragma unroll
            for (int mt = 0; mt < 2; ++mt)
                afrH[mt] = *(const short8_t*)(Hb + (mt * 16 + row16) * 128 +
                                              (((ks * 4 + quad) ^ (row16 & 7)) << 4));
#pragma unroll
            for (int nt = 0; nt < 2; ++nt) {
                short8_t bfr = *(const short8_t*)(sW3 + ks * 4096 +
                                                  (w * 32 + nt * 16 + row16) * 32 + (quad ^ sw) * 8);
                accz[0][nt] = __builtin_amdgcn_mfma_f32_16x16x32_bf16(afrH[0], bfr, accz[0][nt], 0, 0, 0);
                accz[1][nt] = __builtin_amdgcn_mfma_f32_16x16x32_bf16(afrH[1], bfr, accz[1][nt], 0, 0, 0);
            }
        }
        __syncthreads();   // B2: W3(c)+H consumed; W2(c+1) drained here
        if (c < 7) {       // restage W3 (drained by vmcnt(0) at next B1)
#pragma unroll
            for (int i = 0; i < 4; ++i) {
                int f = w * 4 + i;
                int ks = f >> 3;
                int n = (f & 7) * 16 + srow;
                int kc = klin ^ ((n >> 2) & 3);
                gl_lds16(W3t + (size_t)n * 512 + (c + 1) * 64 + ks * 32 + kc * 8,
                         sW3 + f * 512);
            }
        }
    }

    // ---- epilogue: z = accz + b3 + res ; write bf16 + BN stats ----
#pragma unroll
    for (int mt = 0; mt < 2; ++mt) {
#pragma unroll
        for (int nt = 0; nt < 2; ++nt) {
            int cc = w * 32 + nt * 16 + row16;
            float bv = b3[cc];
            float ls = 0.f, lq = 0.f;
#pragma unroll
            for (int r = 0; r < 4; ++r) {
                int rr = m0 + mt * 16 + quad * 4 + r;
                if (rr < NN) {
                    float v = accz[mt][nt][r] + bv + bf2f(res[(size_t)rr * 128 + cc]);
                    outB[(size_t)rr * 128 + cc] = f2bf(v);
                    ls += v;
                    lq += v * v;
                }
            }
            atomicAdd(&s1[cc], ls);
            atomicAdd(&s2[cc], lq);
        }
    }
    __syncthreads();
    if (t < 128) {
        atomicAdd(&stats[t], s1[t]);
        atomicAdd(&stats[128 + t], s2[t]);
    }
}

// ---------------- host ----------------
extern "C" void kernel_launch(void* const* d_in, const int* in_sizes, int n_in,
                              void* d_out, int out_size, void* d_ws, size_t ws_size,
                              hipStream_t stream) {
    const int* ei = (const int*)d_in[2];

    char* p = (char*)d_ws;
    auto alloc = [&](size_t bytes) {
        void* r = (void*)p;
        p += (bytes + 255) & ~(size_t)255;
        return r;
    };
    ushort_t* hB    = (ushort_t*)alloc((size_t)NP * DEMB * 2);   // h (padded)
    ushort_t* h1B   = (ushort_t*)alloc((size_t)NP * DEMB * 2);   // h1 (padded)
    ushort_t* xlB   = (ushort_t*)alloc((size_t)NN * DEMB * 2);   // xl, reused as zB
    unsigned int* hsA  = (unsigned int*)alloc((size_t)NN * 64 * 4);
    unsigned int* hsB_ = (unsigned int*)alloc((size_t)NN * 64 * 4);
    unsigned int* h0p  = (unsigned int*)alloc((size_t)NN * 64 * 4);
    float*    asv   = (float*)alloc((size_t)NN * 8 * 4);
    float*    adv   = (float*)alloc((size_t)NN * 8 * 4);
    float*    gv    = (float*)alloc((size_t)NN * 16 * 4);
    float*    dinvv = (float*)alloc((size_t)NN * 4);
    float*    stats = (float*)alloc(4 * 256 * 4);
    int*      deg   = (int*)alloc((size_t)NN * 4);
    int*      rowp  = (int*)alloc((size_t)(NN + 1) * 4);
    int*      fill  = (int*)alloc((size_t)NN * 4);
    ushort_t* colv  = (ushort_t*)alloc((size_t)EP * 2);
    int*      part  = (int*)alloc(NB_SCAN * 4);
    int*      poff  = (int*)alloc(NB_SCAN * 4);
    int*      flag  = (int*)alloc(256);
    ushort_t* wtg   = (ushort_t*)alloc((size_t)2 * 128 * 128 * 2);
    ushort_t* wt2   = (ushort_t*)alloc((size_t)2 * 512 * 128 * 2);
    ushort_t* wt3   = (ushort_t*)alloc((size_t)2 * 128 * 512 * 2);
    float* xf   = (float*)alloc((size_t)NN * 2 * 4);
    float* Jf   = (float*)alloc((size_t)NN * 4);
    float* l0wF = (float*)alloc(384 * 4);
    float* l0bF = (float*)alloc(128 * 4);
    float* gwF  = (float*)alloc(32768 * 4);
    float* asF  = (float*)alloc(256 * 4);
    float* adF  = (float*)alloc(256 * 4);
    float* w1F  = (float*)alloc(4096 * 4);
    float* b1gF = (float*)alloc(256 * 4);
    float* b1bF = (float*)alloc(256 * 4);
    float* w2F  = (float*)alloc(131072 * 4);
    float* b2F  = (float*)alloc(1024 * 4);
    float* w3F  = (float*)alloc(131072 * 4);
    float* b3F  = (float*)alloc(256 * 4);
    float* b2gF = (float*)alloc(256 * 4);
    float* b2bF = (float*)alloc(256 * 4);

    // ---- dtype detect + batched canonicalize ----
    k_detect<<<1, 64, 0, stream>>>((const unsigned int*)d_in[1], flag);
    CvtArgs ca;
    {
        const int srcIdx[16] = {0, 1, 3, 4, 5, 6, 7, 8, 9, 10, 11, 12, 13, 14, 15, 16};
        float* dsts[16] = {xf, Jf, l0wF, l0bF, gwF, asF, adF, w1F, b1gF, b1bF,
                           w2F, b2F, w3F, b3F, b2gF, b2bF};
        const int ns[16] = {NN * 2, NN, 384, 128, 32768, 256, 256, 4096, 256, 256,
                            131072, 1024, 131072, 256, 256, 256};
        for (int i = 0; i < 16; ++i) { ca.src[i] = d_in[srcIdx[i]]; ca.dst[i] = dsts[i]; ca.n[i] = ns[i]; }
    }
    k_cvt_all<<<dim3(cdiv(131072, 256), 16), 256, 0, stream>>>(ca, flag);

    // ---- CSR build ----
    hipMemsetAsync(deg, 0, (size_t)NN * 4, stream);
    hipMemsetAsync(stats, 0, 4 * 256 * 4, stream);
    k_deg<<<cdiv(EP, 256), 256, 0, stream>>>(ei, deg);
    k_part<<<NB_SCAN, 256, 0, stream>>>(deg, part);
    k_scan2<<<1, 256, 0, stream>>>(part, poff, rowp);
    k_rowp<<<NB_SCAN, 256, 0, stream>>>(deg, poff, rowp, dinvv, fill);
    k_fill<<<cdiv(EP, 256), 256, 0, stream>>>(ei, fill, colv);

    // ---- batched weight transposes (all plain; BM=32 k_ffn needs no k-perm) ----
    TrArgs ta;
    {
        const float* srcs[6] = {gwF, gwF + 16384, w2F, w2F + 65536, w3F, w3F + 65536};
        ushort_t* dsts[6] = {wtg, wtg + 16384, wt2, wt2 + 65536, wt3, wt3 + 65536};
        const int Ks[6] = {128, 128, 128, 128, 512, 512};
        const int Ncs[6] = {128, 128, 512, 512, 128, 128};
        for (int i = 0; i < 6; ++i) {
            ta.src[i] = srcs[i]; ta.dst[i] = dsts[i]; ta.K[i] = Ks[i]; ta.Nc[i] = Ncs[i];
            ta.perm[i] = 0;
        }
    }
    k_tr_all<<<dim3(cdiv(65536, 256), 6), 256, 0, stream>>>(ta);

    // ---- input projection (bf16 h only) ----
    k_lin0<<<cdiv(NN * DEMB, 256), 256, 0, stream>>>(xf, Jf, l0wF, l0bF, hB);

    for (int l = 0; l < 2; ++l) {
        float* st1 = stats + (l * 2 + 0) * 256;
        float* st2 = stats + (l * 2 + 1) * 256;
        ushort_t* zB = xlB;  // reuse xl buffer for z after k_gat is done
        // xl (bf16) = h @ gat_w[l]
        k_gemm64<3><<<dim3(NMT64, 1), 256, 0, stream>>>(hB, wtg + l * 16384, NN, 128, 128,
                                                        nullptr, nullptr, xlB, nullptr);
        k_att<<<cdiv(NN * 8, 256), 256, 0, stream>>>((const unsigned int*)xlB, asF + l * 128,
                                                     adF + l * 128, asv, adv);
        k_gat<<<cdiv(NN * 64, 256), 256, 0, stream>>>(rowp, colv, asv, adv,
                                                      (const unsigned int*)xlB, gv);
        k_z1s<<<512, 256, 0, stream>>>(hB, gv, w1F + l * 2048, st1);
        k_bnapply1<<<cdiv(NN * DEMB, 256), 256, 0, stream>>>(hB, gv, w1F + l * 2048, st1,
                                                             b1gF + l * 128, b1bF + l * 128,
                                                             h1B);
        // fused FFN: z = relu(h1@W2+b2)@W3 + b3 + h1, + BN2 stats
        k_ffn<<<NMT32, 256, 0, stream>>>(h1B, wt2 + l * 65536, wt3 + l * 65536,
                                         b2F + l * 512, b3F + l * 128, h1B, zB, st2);
        if (l == 0) {
            k_bnapply<<<cdiv(NN * DEMB, 256), 256, 0, stream>>>(zB, st2, b2gF, b2bF, hB);
        } else {
            k_bnapply_fin<<<cdiv(NN * 64, 256), 256, 0, stream>>>((const unsigned int*)zB, st2,
                                                                  b2gF + 128, b2bF + 128,
                                                                  dinvv, hsA, h0p);
        }
    }

    // ---- APPNP: 10 steps (slabbed); last writes d_out ----
    unsigned int* pin = hsA;
    unsigned int* pout = hsB_;
    for (int k = 0; k < 10; ++k) {
        int last = (k == 9) ? 1 : 0;
        k_appnp<<<50000, 256, 0, stream>>>(rowp, colv, dinvv, pin, h0p, pout,
                                           Jf, flag, d_out, last);
        unsigned int* tmp = pout;
        pout = pin;
        pin = tmp;
    }
}

// Round 6
// 1149.369 us; speedup vs baseline: 1.1471x; 1.1471x over previous
//
#include <hip/hip_runtime.h>

#define NN 50000
#define NP 50048   // padded rows for global_load_lds tail reads
#define NMT64 782  // cdiv(NN,64)
#define NMT32 1563 // cdiv(NN,32)
#define NE 800000
#define EP (NE + NN)
#define DEMB 128
#define DHID 512
#define NB_SCAN 196  // cdiv(NN,256)

typedef unsigned short ushort_t;
typedef __attribute__((ext_vector_type(8))) short short8_t;
typedef __attribute__((ext_vector_type(4))) float float4_t;

__device__ __forceinline__ float bf2f(ushort_t u) {
    return __uint_as_float(((unsigned int)u) << 16);
}
__device__ __forceinline__ ushort_t f2bf(float f) {
    unsigned int x = __float_as_uint(f);
    x += 0x7fffu + ((x >> 16) & 1u);
    return (ushort_t)(x >> 16);
}
__device__ __forceinline__ float lo16(unsigned int w) { return __uint_as_float(w << 16); }
__device__ __forceinline__ float hi16(unsigned int w) { return __uint_as_float(w & 0xffff0000u); }
__device__ __forceinline__ unsigned int pack2(float a, float b) {
    return (unsigned int)f2bf(a) | ((unsigned int)f2bf(b) << 16);
}
__device__ __forceinline__ void gl_lds16(const ushort_t* g, ushort_t* l) {
    __builtin_amdgcn_global_load_lds(
        (const __attribute__((address_space(1))) void*)g,
        (__attribute__((address_space(3))) void*)l, 16, 0, 0);
}
static inline int cdiv(int a, int b) { return (a + b - 1) / b; }

// ---------------- dtype detect + batched convert ----------------
__global__ void k_detect(const unsigned int* __restrict__ Jw, int* __restrict__ flag) {
    if (threadIdx.x != 0 || blockIdx.x != 0) return;
    int votes = 0;
    for (int i = 0; i < 8; ++i) {
        unsigned int w = Jw[i];
        unsigned int ex = (w >> 23) & 0xFFu;
        if ((w >> 31) == 0u && ex >= 100u && ex <= 126u) votes++;
    }
    *flag = (votes >= 6) ? 1 : 0;
}

struct CvtArgs {
    const void* src[16];
    float* dst[16];
    int n[16];
};
__global__ void k_cvt_all(CvtArgs a, const int* __restrict__ flag) {
    int which = blockIdx.y;
    int i = blockIdx.x * 256 + threadIdx.x;
    if (i >= a.n[which]) return;
    float v;
    if (*flag) v = ((const float*)a.src[which])[i];
    else       v = bf2f(((const ushort_t*)a.src[which])[i]);
    a.dst[which][i] = v;
}

struct TrArgs {
    const float* src[6];
    ushort_t* dst[6];
    int K[6];
    int Nc[6];
    int perm[6];
};
// plain [K][Nc] -> [Nc][K] transpose to bf16 (perm unused: BM=32 k_ffn H-packing
// pairs consecutive hid cols, so the W3 k-permutation is the identity).
__global__ void k_tr_all(TrArgs a) {
    int which = blockIdx.y;
    int idx = blockIdx.x * 256 + threadIdx.x;
    int K = a.K[which], Nc = a.Nc[which];
    if (idx >= K * Nc) return;
    int k = idx / Nc, n = idx - k * Nc;
    a.dst[which][n * K + k] = f2bf(a.src[which][idx]);
}

// ---------------- CSR build ----------------
__global__ void k_deg(const int* __restrict__ ei, int* __restrict__ deg) {
    int e = blockIdx.x * 256 + threadIdx.x;
    if (e >= EP) return;
    int d = (e < NE) ? ei[NE + e] : (e - NE);
    atomicAdd(&deg[d], 1);
}

__global__ void k_part(const int* __restrict__ deg, int* __restrict__ part) {
    __shared__ int sm[256];
    int i = blockIdx.x * 256 + threadIdx.x;
    int v = (i < NN) ? deg[i] : 0;
    sm[threadIdx.x] = v;
    __syncthreads();
    for (int off = 128; off > 0; off >>= 1) {
        if (threadIdx.x < off) sm[threadIdx.x] += sm[threadIdx.x + off];
        __syncthreads();
    }
    if (threadIdx.x == 0) part[blockIdx.x] = sm[0];
}

__global__ void k_scan2(const int* __restrict__ part, int* __restrict__ poff,
                        int* __restrict__ rowp) {
    __shared__ int sm[256];
    int t = threadIdx.x;
    int v = (t < NB_SCAN) ? part[t] : 0;
    sm[t] = v;
    __syncthreads();
    int incl = v;
    for (int off = 1; off < 256; off <<= 1) {
        int u = (t >= off) ? sm[t - off] : 0;
        __syncthreads();
        incl += u;
        sm[t] = incl;
        __syncthreads();
    }
    if (t < NB_SCAN) poff[t] = incl - v;
    if (t == 255) rowp[NN] = sm[255];
}

// rowp + dinv + fill-init fused
__global__ void k_rowp(const int* __restrict__ deg, const int* __restrict__ poff,
                       int* __restrict__ rowp, float* __restrict__ dinv,
                       int* __restrict__ fill) {
    __shared__ int sm[256];
    int i = blockIdx.x * 256 + threadIdx.x;
    int t = threadIdx.x;
    int v = (i < NN) ? deg[i] : 0;
    sm[t] = v;
    __syncthreads();
    int incl = v;
    for (int off = 1; off < 256; off <<= 1) {
        int u = (t >= off) ? sm[t - off] : 0;
        __syncthreads();
        incl += u;
        sm[t] = incl;
        __syncthreads();
    }
    if (i < NN) {
        int rp = poff[blockIdx.x] + incl - v;
        rowp[i] = rp;
        fill[i] = rp;
        dinv[i] = rsqrtf(fmaxf((float)v, 1.0f));
    }
}

__global__ void k_fill(const int* __restrict__ ei, int* __restrict__ fillpos,
                       ushort_t* __restrict__ col) {
    int e = blockIdx.x * 256 + threadIdx.x;
    if (e >= EP) return;
    int s, d;
    if (e < NE) { s = ei[e]; d = ei[NE + e]; } else { s = d = e - NE; }
    int pos = atomicAdd(&fillpos[d], 1);
    col[pos] = (ushort_t)s;
}

// ---------------- elementwise ----------------
__global__ void k_lin0(const float* __restrict__ x, const float* __restrict__ J,
                       const float* __restrict__ w, const float* __restrict__ b,
                       ushort_t* __restrict__ hB) {
    int idx = blockIdx.x * 256 + threadIdx.x;
    if (idx >= NN * DEMB) return;
    int n = idx >> 7, d = idx & 127;
    float v = x[n * 2] * w[d] + x[n * 2 + 1] * w[DEMB + d] + J[n] * w[2 * DEMB + d] + b[d];
    hB[idx] = f2bf(v);
}

__global__ void k_att(const unsigned int* __restrict__ xlB, const float* __restrict__ asrc,
                      const float* __restrict__ adst, float* __restrict__ a_s,
                      float* __restrict__ a_d) {
    int idx = blockIdx.x * 256 + threadIdx.x;
    if (idx >= NN * 8) return;
    int n = idx >> 3, hh = idx & 7;
    const unsigned int* row = xlB + (size_t)n * 64 + hh * 8;
    float s = 0.f, d = 0.f;
#pragma unroll
    for (int c = 0; c < 8; ++c) {
        unsigned int w = row[c];
        float v0 = lo16(w), v1 = hi16(w);
        s += v0 * asrc[hh * 16 + 2 * c] + v1 * asrc[hh * 16 + 2 * c + 1];
        d += v0 * adst[hh * 16 + 2 * c] + v1 * adst[hh * 16 + 2 * c + 1];
    }
    a_s[idx] = s;
    a_d[idx] = d;
}

// BN1 stats pass: recompute z = h + g@w1 (h from bf16), accumulate stats only
__global__ __launch_bounds__(256) void k_z1s(const ushort_t* __restrict__ hB,
                                             const float* __restrict__ g,
                                             const float* __restrict__ w1,
                                             float* __restrict__ stats) {
    int d = threadIdx.x & 127;
    int rstart = blockIdx.x * 2 + (threadIdx.x >> 7);
    int stride = gridDim.x * 2;
    float s1 = 0.f, s2 = 0.f;
    for (int r = rstart; r < NN; r += stride) {
        const float* gr = g + r * 16;
        float s = bf2f(hB[(size_t)r * DEMB + d]);
#pragma unroll
        for (int c = 0; c < 16; ++c) s += gr[c] * w1[c * DEMB + d];
        s1 += s;
        s2 += s * s;
    }
    __shared__ float b1[256], b2[256];
    b1[threadIdx.x] = s1;
    b2[threadIdx.x] = s2;
    __syncthreads();
    if (threadIdx.x < 128) {
        atomicAdd(&stats[threadIdx.x], b1[threadIdx.x] + b1[threadIdx.x + 128]);
        atomicAdd(&stats[128 + threadIdx.x], b2[threadIdx.x] + b2[threadIdx.x + 128]);
    }
}

// BN1 apply with recompute (h from bf16); out h1 bf16 only
__global__ void k_bnapply1(const ushort_t* __restrict__ hB, const float* __restrict__ g,
                           const float* __restrict__ w1, const float* __restrict__ stats,
                           const float* __restrict__ gam, const float* __restrict__ bet,
                           ushort_t* __restrict__ outB) {
    int idx = blockIdx.x * 256 + threadIdx.x;
    if (idx >= NN * DEMB) return;
    int n = idx >> 7, d = idx & 127;
    float s = bf2f(hB[idx]);
    const float* gr = g + n * 16;
#pragma unroll
    for (int c = 0; c < 16; ++c) s += gr[c] * w1[c * DEMB + d];
    const float invN = 1.0f / (float)NN;
    float mu = stats[d] * invN;
    float var = stats[128 + d] * invN - mu * mu;
    float rs = rsqrtf(fmaxf(var, 0.f) + 1e-5f);
    float v = gam[d] * (s - mu) * rs + bet[d];
    outB[idx] = f2bf(v);
}

// BN2 apply (layer 0): z from bf16; out hB bf16
__global__ void k_bnapply(const ushort_t* __restrict__ zB, const float* __restrict__ stats,
                          const float* __restrict__ gam, const float* __restrict__ bet,
                          ushort_t* __restrict__ outB) {
    int idx = blockIdx.x * 256 + threadIdx.x;
    if (idx >= NN * DEMB) return;
    int d = idx & 127;
    const float invN = 1.0f / (float)NN;
    float mu = stats[d] * invN;
    float var = stats[128 + d] * invN - mu * mu;
    float rs = rsqrtf(fmaxf(var, 0.f) + 1e-5f);
    float v = gam[d] * (bf2f(zB[idx]) - mu) * rs + bet[d];
    outB[idx] = f2bf(v);
}

// BN2 apply (layer 1, final): z from bf16; emit APPNP inputs in SLAB-MAJOR
// layout [4 slabs][NN][16 u32] (slab q = dims [32q,32q+32))
__global__ void k_bnapply_fin(const unsigned int* __restrict__ zB, const float* __restrict__ stats,
                              const float* __restrict__ gam, const float* __restrict__ bet,
                              const float* __restrict__ dinv,
                              unsigned int* __restrict__ hs, unsigned int* __restrict__ h0p) {
    int idx = blockIdx.x * 256 + threadIdx.x;
    if (idx >= NN * 64) return;
    int n = idx >> 6, j = idx & 63;
    int d0 = j * 2;
    const float invN = 1.0f / (float)NN;
    unsigned int zw = zB[idx];
    float z0 = lo16(zw), z1 = hi16(zw);
    float mu0 = stats[d0] * invN, mu1 = stats[d0 + 1] * invN;
    float v0 = stats[128 + d0] * invN - mu0 * mu0;
    float v1 = stats[128 + d0 + 1] * invN - mu1 * mu1;
    float rs0 = rsqrtf(fmaxf(v0, 0.f) + 1e-5f);
    float rs1 = rsqrtf(fmaxf(v1, 0.f) + 1e-5f);
    float a = gam[d0] * (z0 - mu0) * rs0 + bet[d0];
    float b = gam[d0 + 1] * (z1 - mu1) * rs1 + bet[d0 + 1];
    float di = dinv[n];
    int q = j >> 4, dd = j & 15;
    size_t o = (size_t)q * NN * 16 + (size_t)n * 16 + dd;
    hs[o] = pack2(di * a, di * b);
    h0p[o] = pack2(a, b);
}

// ---------------- GAT: single-pass softmax-aggregate (wave per node) ----------------
__global__ __launch_bounds__(256) void k_gat(const int* __restrict__ rowp,
                                             const ushort_t* __restrict__ col,
                                             const float* __restrict__ a_s, const float* __restrict__ a_d,
                                             const unsigned int* __restrict__ xlB, float* __restrict__ g) {
    int wid = (blockIdx.x * 256 + threadIdx.x) >> 6;
    int lane = threadIdx.x & 63;
    if (wid >= NN) return;
    int p0 = rowp[wid], p1 = rowp[wid + 1];
    int hh = lane >> 3;
    float ad2 = a_d[wid * 8 + hh];
    float acc0 = 0.f, acc1 = 0.f, s = 0.f;
    int p = p0;
    while (p < p1) {
        int cnt = p1 - p;
        if (cnt > 64) cnt = 64;
        int pl = p + lane;
        int jv = (int)col[pl < p1 ? pl : (p1 - 1)];
        int i = 0;
        for (; i + 8 <= cnt; i += 8) {
            int j0 = __shfl(jv, i),     j1 = __shfl(jv, i + 1);
            int j2 = __shfl(jv, i + 2), j3 = __shfl(jv, i + 3);
            int j4 = __shfl(jv, i + 4), j5 = __shfl(jv, i + 5);
            int j6 = __shfl(jv, i + 6), j7 = __shfl(jv, i + 7);
            float e0 = a_s[j0 * 8 + hh] + ad2, e1 = a_s[j1 * 8 + hh] + ad2;
            float e2 = a_s[j2 * 8 + hh] + ad2, e3 = a_s[j3 * 8 + hh] + ad2;
            float e4 = a_s[j4 * 8 + hh] + ad2, e5 = a_s[j5 * 8 + hh] + ad2;
            float e6 = a_s[j6 * 8 + hh] + ad2, e7 = a_s[j7 * 8 + hh] + ad2;
            unsigned int w0 = xlB[j0 * 64 + lane], w1 = xlB[j1 * 64 + lane];
            unsigned int w2 = xlB[j2 * 64 + lane], w3 = xlB[j3 * 64 + lane];
            unsigned int w4 = xlB[j4 * 64 + lane], w5 = xlB[j5 * 64 + lane];
            unsigned int w6 = xlB[j6 * 64 + lane], w7 = xlB[j7 * 64 + lane];
            e0 = e0 > 0.f ? e0 : 0.2f * e0;  e1 = e1 > 0.f ? e1 : 0.2f * e1;
            e2 = e2 > 0.f ? e2 : 0.2f * e2;  e3 = e3 > 0.f ? e3 : 0.2f * e3;
            e4 = e4 > 0.f ? e4 : 0.2f * e4;  e5 = e5 > 0.f ? e5 : 0.2f * e5;
            e6 = e6 > 0.f ? e6 : 0.2f * e6;  e7 = e7 > 0.f ? e7 : 0.2f * e7;
            float al0 = __expf(e0), al1 = __expf(e1), al2 = __expf(e2), al3 = __expf(e3);
            float al4 = __expf(e4), al5 = __expf(e5), al6 = __expf(e6), al7 = __expf(e7);
            s += al0 + al1 + al2 + al3 + al4 + al5 + al6 + al7;
            acc0 += al0 * lo16(w0) + al1 * lo16(w1) + al2 * lo16(w2) + al3 * lo16(w3) +
                    al4 * lo16(w4) + al5 * lo16(w5) + al6 * lo16(w6) + al7 * lo16(w7);
            acc1 += al0 * hi16(w0) + al1 * hi16(w1) + al2 * hi16(w2) + al3 * hi16(w3) +
                    al4 * hi16(w4) + al5 * hi16(w5) + al6 * hi16(w6) + al7 * hi16(w7);
        }
        for (; i < cnt; ++i) {
            int j = __shfl(jv, i);
            float e = a_s[j * 8 + hh] + ad2;
            e = e > 0.f ? e : 0.2f * e;
            float al = __expf(e);
            unsigned int w = xlB[j * 64 + lane];
            s += al;
            acc0 += al * lo16(w);
            acc1 += al * hi16(w);
        }
        p += cnt;
    }
    float inv = 1.f / s;
    acc0 *= inv;
    acc1 *= inv;
    acc0 += __shfl_xor(acc0, 8);  acc1 += __shfl_xor(acc1, 8);
    acc0 += __shfl_xor(acc0, 16); acc1 += __shfl_xor(acc1, 16);
    acc0 += __shfl_xor(acc0, 32); acc1 += __shfl_xor(acc1, 32);
    if (lane < 8) ((float2*)g)[wid * 8 + lane] = make_float2(acc0, acc1);
}

// ---------------- APPNP step: dimension-slabbed gather, 8-deep ILP ----------------
// hs/h0p layout [4 slabs][NN][16 u32]; slab q holds dims [32q,32q+32).
// Wave = 1 node x 1 slab: 64 lanes = 4 edge-slots x 16 dims. Block->slab map
// (b&7)>>1 rides the XCD round-robin: each XCD touches ONE 3.2MB slab ->
// L2-resident gather (round-5: FETCH 45.5 vs 90.8 MB/step un-slabbed).
// Round-5 lesson: 2 gathers in flight = latency-bound (84us). This version
// issues 8 independent predicated 64B gathers per 32-edge stride (clamped
// slots re-hit the last line ~free), matching the old kernel's ILP.
__global__ __launch_bounds__(256) void k_appnp(const int* __restrict__ rowp,
                                               const ushort_t* __restrict__ col,
                                               const float* __restrict__ dinv,
                                               const unsigned int* __restrict__ hs,
                                               const unsigned int* __restrict__ h0p,
                                               unsigned int* __restrict__ hs_out,
                                               const float* __restrict__ Jf,
                                               const int* __restrict__ flag,
                                               void* __restrict__ out, int writeOut) {
    int b = blockIdx.x;
    int w = threadIdx.x >> 6, lane = threadIdx.x & 63;
    int s = (b & 7) >> 1;                 // slab (2 XCDs per slab)
    int i = ((b >> 3) << 1) + (b & 1);    // within-slab node-group [0,12500)
    int n = i * 4 + w;                    // node (< 50000 exactly)
    int es = lane >> 4, d = lane & 15;
    int p0 = rowp[n], p1 = rowp[n + 1];
    const unsigned int* hsq = hs + (size_t)s * NN * 16;
    unsigned int hw = h0p[(size_t)s * NN * 16 + (size_t)n * 16 + d];  // hoisted
    float di = dinv[n];
    float a0 = 0.f, a1 = 0.f;
    int p = p0;
    while (p < p1) {
        int cnt = p1 - p;
        if (cnt > 64) cnt = 64;
        int pl = p + lane;
        int jv = (int)col[pl < p1 ? pl : (p1 - 1)];
        int lim = cnt - 1;
        for (int ii = 0; ii < cnt; ii += 32) {
            int q0 = ii + es,      q1 = ii + 4 + es,  q2 = ii + 8 + es,  q3 = ii + 12 + es;
            int q4 = ii + 16 + es, q5 = ii + 20 + es, q6 = ii + 24 + es, q7 = ii + 28 + es;
            int j0 = __shfl(jv, q0 < lim ? q0 : lim), j1 = __shfl(jv, q1 < lim ? q1 : lim);
            int j2 = __shfl(jv, q2 < lim ? q2 : lim), j3 = __shfl(jv, q3 < lim ? q3 : lim);
            int j4 = __shfl(jv, q4 < lim ? q4 : lim), j5 = __shfl(jv, q5 < lim ? q5 : lim);
            int j6 = __shfl(jv, q6 < lim ? q6 : lim), j7 = __shfl(jv, q7 < lim ? q7 : lim);
            unsigned int w0 = hsq[j0 * 16 + d], w1 = hsq[j1 * 16 + d];
            unsigned int w2 = hsq[j2 * 16 + d], w3 = hsq[j3 * 16 + d];
            unsigned int w4 = hsq[j4 * 16 + d], w5 = hsq[j5 * 16 + d];
            unsigned int w6 = hsq[j6 * 16 + d], w7 = hsq[j7 * 16 + d];
            a0 += ((q0 <= lim) ? lo16(w0) : 0.f) + ((q1 <= lim) ? lo16(w1) : 0.f) +
                  ((q2 <= lim) ? lo16(w2) : 0.f) + ((q3 <= lim) ? lo16(w3) : 0.f) +
                  ((q4 <= lim) ? lo16(w4) : 0.f) + ((q5 <= lim) ? lo16(w5) : 0.f) +
                  ((q6 <= lim) ? lo16(w6) : 0.f) + ((q7 <= lim) ? lo16(w7) : 0.f);
            a1 += ((q0 <= lim) ? hi16(w0) : 0.f) + ((q1 <= lim) ? hi16(w1) : 0.f) +
                  ((q2 <= lim) ? hi16(w2) : 0.f) + ((q3 <= lim) ? hi16(w3) : 0.f) +
                  ((q4 <= lim) ? hi16(w4) : 0.f) + ((q5 <= lim) ? hi16(w5) : 0.f) +
                  ((q6 <= lim) ? hi16(w6) : 0.f) + ((q7 <= lim) ? hi16(w7) : 0.f);
        }
        p += cnt;
    }
    a0 += __shfl_xor(a0, 16); a1 += __shfl_xor(a1, 16);
    a0 += __shfl_xor(a0, 32); a1 += __shfl_xor(a1, 32);
    float n0 = 0.9f * di * a0 + 0.1f * lo16(hw);
    float n1 = 0.9f * di * a1 + 0.1f * hi16(hw);
    if (!writeOut) {
        if (es == 0)
            hs_out[(size_t)s * NN * 16 + (size_t)n * 16 + d] = pack2(di * n0, di * n1);
    } else if (es == 0) {
        size_t base = (size_t)n * 129 + s * 32 + 2 * d;
        if (*flag) {
            float* o = (float*)out;
            o[base] = n0;
            o[base + 1] = n1;
            if (s == 0 && d == 0) o[(size_t)n * 129 + 128] = Jf[n];
        } else {
            ushort_t* o = (ushort_t*)out;
            o[base] = f2bf(n0);
            o[base + 1] = f2bf(n1);
            if (s == 0 && d == 0) o[(size_t)n * 129 + 128] = f2bf(Jf[n]);
        }
    }
}

// ---------------- 64x128-tile MFMA GEMM, double-buffered ----------
// MODE 3: outB = bf16(acc)   (used for xl = h @ gat_w)
template <int MODE>
__global__ __launch_bounds__(256) void k_gemm64(const ushort_t* __restrict__ A,
                                                const ushort_t* __restrict__ Bt,
                                                int M, int K, int Nc,
                                                const float* __restrict__ bias,
                                                const ushort_t* __restrict__ res,
                                                ushort_t* __restrict__ outB,
                                                float* __restrict__ stats) {
    __shared__ __align__(16) ushort_t lsA[2][64 * 32];
    __shared__ __align__(16) ushort_t lsB[2][128 * 32];
    int t = threadIdx.x;
    int m0 = blockIdx.x * 64;
    int n0 = blockIdx.y * 128;
    int w = t >> 6, lane = t & 63;
    int row16 = lane & 15, quad = lane >> 4;
    int nbase = w * 32;
    float4_t acc[8];
#pragma unroll
    for (int i = 0; i < 8; ++i) acc[i] = (float4_t){0.f, 0.f, 0.f, 0.f};
    int lrow = lane >> 2;
    int lcol = (lane & 3) * 8;
    const ushort_t* gA  = A  + (size_t)(m0 + w * 16 + lrow) * K + lcol;
    const ushort_t* gB0 = Bt + (size_t)(n0 + w * 32 + lrow) * K + lcol;
    const ushort_t* gB1 = Bt + (size_t)(n0 + w * 32 + 16 + lrow) * K + lcol;
    ushort_t* dA  = &lsA[0][0] + (w * 16) * 32;
    ushort_t* dB0 = &lsB[0][0] + (w * 32) * 32;
    ushort_t* dB1 = &lsB[0][0] + (w * 32 + 16) * 32;
    const int bufStrideA = 64 * 32, bufStrideB = 128 * 32;
    const int nK = K >> 5;
    gl_lds16(gA, dA);
    gl_lds16(gB0, dB0);
    gl_lds16(gB1, dB1);
    for (int kb = 0; kb < nK; ++kb) {
        __syncthreads();
        int nb = kb + 1;
        if (nb < nK) {
            int b = nb & 1;
            int k0 = nb << 5;
            gl_lds16(gA + k0, dA + b * bufStrideA);
            gl_lds16(gB0 + k0, dB0 + b * bufStrideB);
            gl_lds16(gB1 + k0, dB1 + b * bufStrideB);
        }
        const ushort_t* la = &lsA[kb & 1][0];
        const ushort_t* lb = &lsB[kb & 1][0];
        short8_t afr[4], bfr[2];
#pragma unroll
        for (int i = 0; i < 4; ++i)
            afr[i] = *(const short8_t*)(la + (i * 16 + row16) * 32 + quad * 8);
#pragma unroll
        for (int i = 0; i < 2; ++i)
            bfr[i] = *(const short8_t*)(lb + (nbase + i * 16 + row16) * 32 + quad * 8);
#pragma unroll
        for (int mt = 0; mt < 4; ++mt)
#pragma unroll
            for (int nt = 0; nt < 2; ++nt)
                acc[mt * 2 + nt] = __builtin_amdgcn_mfma_f32_16x16x32_bf16(
                    afr[mt], bfr[nt], acc[mt * 2 + nt], 0, 0, 0);
    }
#pragma unroll
    for (int mt = 0; mt < 4; ++mt) {
#pragma unroll
        for (int nt = 0; nt < 2; ++nt) {
            int cc = n0 + nbase + nt * 16 + row16;
#pragma unroll
            for (int r = 0; r < 4; ++r) {
                int rr = m0 + mt * 16 + quad * 4 + r;
                if (rr < M) {
                    outB[(size_t)rr * Nc + cc] = f2bf(acc[mt * 2 + nt][r]);
                }
            }
        }
    }
}

// ---------------- fused FFN, BM=32: z = relu(A@W2+b2)@W3 + b3 + res, + BN stats ----
// A:[NP][128] bf16, W2t:[512 n][128 k] bf16, W3t:[128 n][512 k] bf16 (plain).
// 1563 blocks (~6.1/CU), LDS = 16K(W2) + 16K(W3) + 8K(A prologue -> H 4K + stats 1K)
// = 40KB -> 4 blocks/CU, 16 waves/CU. Two barriers/chunk with staggered
// single-buffer restaging. H pairing consecutive -> no W3 k-permutation.
__global__ __launch_bounds__(256, 4) void k_ffn(const ushort_t* __restrict__ A,
                                                const ushort_t* __restrict__ W2t,
                                                const ushort_t* __restrict__ W3t,
                                                const float* __restrict__ b2,
                                                const float* __restrict__ b3,
                                                const ushort_t* __restrict__ res,
                                                ushort_t* __restrict__ outB,
                                                float* __restrict__ stats) {
    __shared__ __align__(16) ushort_t sW2[4 * 64 * 32];   // 16KB [kb][64 n][32 k]
    __shared__ __align__(16) ushort_t sW3[2 * 128 * 32];  // 16KB [ks][128 n][32 k]
    __shared__ __align__(16) ushort_t sAH[4 * 1024];      // 8KB A prologue [kb][32 r][32 k]; then H+stats
    int t = threadIdx.x;
    int w = t >> 6, lane = t & 63;       // w = n-quarter
    int m0 = blockIdx.x * 32;
    int row16 = lane & 15, quad = lane >> 4;
    int sw = (row16 >> 2) & 3;   // read-side k-group swizzle
    int srow = lane >> 2;        // staging: row within a 16-row issue
    int klin = lane & 3;         // staging: linear k-group this lane fills

    // ---- prologue staging: A tile (wave w -> kb=w), W2 chunk 0, W3 chunk 0 ----
#pragma unroll
    for (int i = 0; i < 2; ++i) {
        int row = i * 16 + srow;
        int kc = klin ^ ((row >> 2) & 3);
        gl_lds16(A + (size_t)(m0 + row) * 128 + w * 32 + kc * 8,
                 sAH + w * 1024 + i * 512);
    }
#pragma unroll
    for (int i = 0; i < 4; ++i) {
        int n = i * 16 + srow;
        int kc = klin ^ ((n >> 2) & 3);
        gl_lds16(W2t + (size_t)n * 128 + w * 32 + kc * 8,
                 sW2 + w * 2048 + i * 512);
        int f = w * 4 + i;
        int ks = f >> 3;
        int n3 = (f & 7) * 16 + srow;
        int kc3 = klin ^ ((n3 >> 2) & 3);
        gl_lds16(W3t + (size_t)n3 * 512 + ks * 32 + kc3 * 8,
                 sW3 + f * 512);
    }
    __syncthreads();

    // hoist A fragments (chunk-invariant): afrA[mt][kb], 32 VGPRs
    short8_t afrA[2][4];
#pragma unroll
    for (int mt = 0; mt < 2; ++mt)
#pragma unroll
        for (int kb = 0; kb < 4; ++kb)
            afrA[mt][kb] = *(const short8_t*)(sAH + kb * 1024 +
                                              (mt * 16 + row16) * 32 + (quad ^ sw) * 8);
    __syncthreads();   // A region free -> H + stats

    char* Hb = (char*)sAH;             // 4KB H: 32 rows x 128B
    float* s1 = (float*)(Hb + 4096);   // 128 f32
    float* s2 = s1 + 128;
    if (t < 128) { s1[t] = 0.f; s2[t] = 0.f; }

    float4_t accz[2][2];
#pragma unroll
    for (int mt = 0; mt < 2; ++mt)
#pragma unroll
        for (int nt = 0; nt < 2; ++nt) accz[mt][nt] = (float4_t){0.f, 0.f, 0.f, 0.f};

    for (int c = 0; c < 8; ++c) {
        // ---- phase 1: hid_c = relu(A @ W2[:, 64c:64c+64] + b2), 16-col slice w ----
        float b2v = b2[c * 64 + w * 16 + row16];
        float4_t acch[2];
        acch[0] = (float4_t){0.f, 0.f, 0.f, 0.f};
        acch[1] = (float4_t){0.f, 0.f, 0.f, 0.f};
#pragma unroll
        for (int kb = 0; kb < 4; ++kb) {
            short8_t b0 = *(const short8_t*)(sW2 + kb * 2048 +
                                             (w * 16 + row16) * 32 + (quad ^ sw) * 8);
            acch[0] = __builtin_amdgcn_mfma_f32_16x16x32_bf16(afrA[0][kb], b0, acch[0], 0, 0, 0);
            acch[1] = __builtin_amdgcn_mfma_f32_16x16x32_bf16(afrA[1][kb], b0, acch[1], 0, 0, 0);
        }
        // relu+bias -> packed H (pair col with col^1 via shfl; even lanes write b32)
#pragma unroll
        for (int mt = 0; mt < 2; ++mt) {
#pragma unroll
            for (int r = 0; r < 4; ++r) {
                int row = mt * 16 + quad * 4 + r;
                float v = acch[mt][r] + b2v;
                v = v > 0.f ? v : 0.f;
                float vo = __shfl_xor(v, 1);
                if (!(row16 & 1)) {
                    int kidx = w * 8 + (row16 >> 1);
                    int byteOff = row * 128 + ((((kidx >> 2) ^ (row & 7))) << 4) + (kidx & 3) * 4;
                    *(unsigned int*)(Hb + byteOff) = pack2(v, vo);
                }
            }
        }
        __syncthreads();   // B1: H visible; W2(c) fully consumed
        if (c < 7) {       // restage W2 (drained by vmcnt(0) at B2)
#pragma unroll
            for (int i = 0; i < 4; ++i) {
                int n = i * 16 + srow;
                int kc = klin ^ ((n >> 2) & 3);
                gl_lds16(W2t + (size_t)((c + 1) * 64 + n) * 128 + w * 32 + kc * 8,
                         sW2 + w * 2048 + i * 512);
            }
        }
        // ---- phase 2: accz += hid_c @ W3[64c:64c+64, :], 32-col slice w ----
#pragma unroll
        for (int ks = 0; ks < 2; ++ks) {
            short8_t afrH[2];
#pragma unroll
            for (int mt = 0; mt < 2; ++mt)
                afrH[mt] = *(const short8_t*)(Hb + (mt * 16 + row16) * 128 +
                                              (((ks * 4 + quad) ^ (row16 & 7)) << 4));
#pragma unroll
            for (int nt = 0; nt < 2; ++nt) {
                short8_t bfr = *(const short8_t*)(sW3 + ks * 4096 +
                                                  (w * 32 + nt * 16 + row16) * 32 + (quad ^ sw) * 8);
                accz[0][nt] = __builtin_amdgcn_mfma_f32_16x16x32_bf16(afrH[0], bfr, accz[0][nt], 0, 0, 0);
                accz[1][nt] = __builtin_amdgcn_mfma_f32_16x16x32_bf16(afrH[1], bfr, accz[1][nt], 0, 0, 0);
            }
        }
        __syncthreads();   // B2: W3(c)+H consumed; W2(c+1) drained here
        if (c < 7) {       // restage W3 (drained by vmcnt(0) at next B1)
#pragma unroll
            for (int i = 0; i < 4; ++i) {
                int f = w * 4 + i;
                int ks = f >> 3;
                int n = (f & 7) * 16 + srow;
                int kc = klin ^ ((n >> 2) & 3);
                gl_lds16(W3t + (size_t)n * 512 + (c + 1) * 64 + ks * 32 + kc * 8,
                         sW3 + f * 512);
            }
        }
    }

    // ---- epilogue: z = accz + b3 + res ; write bf16 + BN stats ----
#pragma unroll
    for (int mt = 0; mt < 2; ++mt) {
#pragma unroll
        for (int nt = 0; nt < 2; ++nt) {
            int cc = w * 32 + nt * 16 + row16;
            float bv = b3[cc];
            float ls = 0.f, lq = 0.f;
#pragma unroll
            for (int r = 0; r < 4; ++r) {
                int rr = m0 + mt * 16 + quad * 4 + r;
                if (rr < NN) {
                    float v = accz[mt][nt][r] + bv + bf2f(res[(size_t)rr * 128 + cc]);
                    outB[(size_t)rr * 128 + cc] = f2bf(v);
                    ls += v;
                    lq += v * v;
                }
            }
            atomicAdd(&s1[cc], ls);
            atomicAdd(&s2[cc], lq);
        }
    }
    __syncthreads();
    if (t < 128) {
        atomicAdd(&stats[t], s1[t]);
        atomicAdd(&stats[128 + t], s2[t]);
    }
}

// ---------------- host ----------------
extern "C" void kernel_launch(void* const* d_in, const int* in_sizes, int n_in,
                              void* d_out, int out_size, void* d_ws, size_t ws_size,
                              hipStream_t stream) {
    const int* ei = (const int*)d_in[2];

    char* p = (char*)d_ws;
    auto alloc = [&](size_t bytes) {
        void* r = (void*)p;
        p += (bytes + 255) & ~(size_t)255;
        return r;
    };
    ushort_t* hB    = (ushort_t*)alloc((size_t)NP * DEMB * 2);   // h (padded)
    ushort_t* h1B   = (ushort_t*)alloc((size_t)NP * DEMB * 2);   // h1 (padded)
    ushort_t* xlB   = (ushort_t*)alloc((size_t)NN * DEMB * 2);   // xl, reused as zB
    unsigned int* hsA  = (unsigned int*)alloc((size_t)NN * 64 * 4);
    unsigned int* hsB_ = (unsigned int*)alloc((size_t)NN * 64 * 4);
    unsigned int* h0p  = (unsigned int*)alloc((size_t)NN * 64 * 4);
    float*    asv   = (float*)alloc((size_t)NN * 8 * 4);
    float*    adv   = (float*)alloc((size_t)NN * 8 * 4);
    float*    gv    = (float*)alloc((size_t)NN * 16 * 4);
    float*    dinvv = (float*)alloc((size_t)NN * 4);
    float*    stats = (float*)alloc(4 * 256 * 4);
    int*      deg   = (int*)alloc((size_t)NN * 4);
    int*      rowp  = (int*)alloc((size_t)(NN + 1) * 4);
    int*      fill  = (int*)alloc((size_t)NN * 4);
    ushort_t* colv  = (ushort_t*)alloc((size_t)EP * 2);
    int*      part  = (int*)alloc(NB_SCAN * 4);
    int*      poff  = (int*)alloc(NB_SCAN * 4);
    int*      flag  = (int*)alloc(256);
    ushort_t* wtg   = (ushort_t*)alloc((size_t)2 * 128 * 128 * 2);
    ushort_t* wt2   = (ushort_t*)alloc((size_t)2 * 512 * 128 * 2);
    ushort_t* wt3   = (ushort_t*)alloc((size_t)2 * 128 * 512 * 2);
    float* xf   = (float*)alloc((size_t)NN * 2 * 4);
    float* Jf   = (float*)alloc((size_t)NN * 4);
    float* l0wF = (float*)alloc(384 * 4);
    float* l0bF = (float*)alloc(128 * 4);
    float* gwF  = (float*)alloc(32768 * 4);
    float* asF  = (float*)alloc(256 * 4);
    float* adF  = (float*)alloc(256 * 4);
    float* w1F  = (float*)alloc(4096 * 4);
    float* b1gF = (float*)alloc(256 * 4);
    float* b1bF = (float*)alloc(256 * 4);
    float* w2F  = (float*)alloc(131072 * 4);
    float* b2F  = (float*)alloc(1024 * 4);
    float* w3F  = (float*)alloc(131072 * 4);
    float* b3F  = (float*)alloc(256 * 4);
    float* b2gF = (float*)alloc(256 * 4);
    float* b2bF = (float*)alloc(256 * 4);

    // ---- dtype detect + batched canonicalize ----
    k_detect<<<1, 64, 0, stream>>>((const unsigned int*)d_in[1], flag);
    CvtArgs ca;
    {
        const int srcIdx[16] = {0, 1, 3, 4, 5, 6, 7, 8, 9, 10, 11, 12, 13, 14, 15, 16};
        float* dsts[16] = {xf, Jf, l0wF, l0bF, gwF, asF, adF, w1F, b1gF, b1bF,
                           w2F, b2F, w3F, b3F, b2gF, b2bF};
        const int ns[16] = {NN * 2, NN, 384, 128, 32768, 256, 256, 4096, 256, 256,
                            131072, 1024, 131072, 256, 256, 256};
        for (int i = 0; i < 16; ++i) { ca.src[i] = d_in[srcIdx[i]]; ca.dst[i] = dsts[i]; ca.n[i] = ns[i]; }
    }
    k_cvt_all<<<dim3(cdiv(131072, 256), 16), 256, 0, stream>>>(ca, flag);

    // ---- CSR build ----
    hipMemsetAsync(deg, 0, (size_t)NN * 4, stream);
    hipMemsetAsync(stats, 0, 4 * 256 * 4, stream);
    k_deg<<<cdiv(EP, 256), 256, 0, stream>>>(ei, deg);
    k_part<<<NB_SCAN, 256, 0, stream>>>(deg, part);
    k_scan2<<<1, 256, 0, stream>>>(part, poff, rowp);
    k_rowp<<<NB_SCAN, 256, 0, stream>>>(deg, poff, rowp, dinvv, fill);
    k_fill<<<cdiv(EP, 256), 256, 0, stream>>>(ei, fill, colv);

    // ---- batched weight transposes (all plain; BM=32 k_ffn needs no k-perm) ----
    TrArgs ta;
    {
        const float* srcs[6] = {gwF, gwF + 16384, w2F, w2F + 65536, w3F, w3F + 65536};
        ushort_t* dsts[6] = {wtg, wtg + 16384, wt2, wt2 + 65536, wt3, wt3 + 65536};
        const int Ks[6] = {128, 128, 128, 128, 512, 512};
        const int Ncs[6] = {128, 128, 512, 512, 128, 128};
        for (int i = 0; i < 6; ++i) {
            ta.src[i] = srcs[i]; ta.dst[i] = dsts[i]; ta.K[i] = Ks[i]; ta.Nc[i] = Ncs[i];
            ta.perm[i] = 0;
        }
    }
    k_tr_all<<<dim3(cdiv(65536, 256), 6), 256, 0, stream>>>(ta);

    // ---- input projection (bf16 h only) ----
    k_lin0<<<cdiv(NN * DEMB, 256), 256, 0, stream>>>(xf, Jf, l0wF, l0bF, hB);

    for (int l = 0; l < 2; ++l) {
        float* st1 = stats + (l * 2 + 0) * 256;
        float* st2 = stats + (l * 2 + 1) * 256;
        ushort_t* zB = xlB;  // reuse xl buffer for z after k_gat is done
        // xl (bf16) = h @ gat_w[l]
        k_gemm64<3><<<dim3(NMT64, 1), 256, 0, stream>>>(hB, wtg + l * 16384, NN, 128, 128,
                                                        nullptr, nullptr, xlB, nullptr);
        k_att<<<cdiv(NN * 8, 256), 256, 0, stream>>>((const unsigned int*)xlB, asF + l * 128,
                                                     adF + l * 128, asv, adv);
        k_gat<<<cdiv(NN * 64, 256), 256, 0, stream>>>(rowp, colv, asv, adv,
                                                      (const unsigned int*)xlB, gv);
        k_z1s<<<512, 256, 0, stream>>>(hB, gv, w1F + l * 2048, st1);
        k_bnapply1<<<cdiv(NN * DEMB, 256), 256, 0, stream>>>(hB, gv, w1F + l * 2048, st1,
                                                             b1gF + l * 128, b1bF + l * 128,
                                                             h1B);
        // fused FFN: z = relu(h1@W2+b2)@W3 + b3 + h1, + BN2 stats
        k_ffn<<<NMT32, 256, 0, stream>>>(h1B, wt2 + l * 65536, wt3 + l * 65536,
                                         b2F + l * 512, b3F + l * 128, h1B, zB, st2);
        if (l == 0) {
            k_bnapply<<<cdiv(NN * DEMB, 256), 256, 0, stream>>>(zB, st2, b2gF, b2bF, hB);
        } else {
            k_bnapply_fin<<<cdiv(NN * 64, 256), 256, 0, stream>>>((const unsigned int*)zB, st2,
                                                                  b2gF + 128, b2bF + 128,
                                                                  dinvv, hsA, h0p);
        }
    }

    // ---- APPNP: 10 steps (slabbed); last writes d_out ----
    unsigned int* pin = hsA;
    unsigned int* pout = hsB_;
    for (int k = 0; k < 10; ++k) {
        int last = (k == 9) ? 1 : 0;
        k_appnp<<<50000, 256, 0, stream>>>(rowp, colv, dinvv, pin, h0p, pout,
                                           Jf, flag, d_out, last);
        unsigned int* tmp = pout;
        pout = pin;
        pin = tmp;
    }
}

// Round 7
// 893.789 us; speedup vs baseline: 1.4751x; 1.2860x over previous
//
#include <hip/hip_runtime.h>

#define NN 50000
#define NP 50048   // padded rows for global_load_lds tail reads
#define NMT64 782  // cdiv(NN,64)
#define NE 800000
#define EP (NE + NN)
#define DEMB 128
#define DHID 512
#define NB_SCAN 196  // cdiv(NN,256)

typedef unsigned short ushort_t;
typedef __attribute__((ext_vector_type(8))) short short8_t;
typedef __attribute__((ext_vector_type(4))) float float4_t;

__device__ __forceinline__ float bf2f(ushort_t u) {
    return __uint_as_float(((unsigned int)u) << 16);
}
__device__ __forceinline__ ushort_t f2bf(float f) {
    unsigned int x = __float_as_uint(f);
    x += 0x7fffu + ((x >> 16) & 1u);
    return (ushort_t)(x >> 16);
}
__device__ __forceinline__ float lo16(unsigned int w) { return __uint_as_float(w << 16); }
__device__ __forceinline__ float hi16(unsigned int w) { return __uint_as_float(w & 0xffff0000u); }
__device__ __forceinline__ unsigned int pack2(float a, float b) {
    return (unsigned int)f2bf(a) | ((unsigned int)f2bf(b) << 16);
}
__device__ __forceinline__ void gl_lds16(const ushort_t* g, ushort_t* l) {
    __builtin_amdgcn_global_load_lds(
        (const __attribute__((address_space(1))) void*)g,
        (__attribute__((address_space(3))) void*)l, 16, 0, 0);
}
static inline int cdiv(int a, int b) { return (a + b - 1) / b; }

// ---------------- dtype detect + batched convert ----------------
__global__ void k_detect(const unsigned int* __restrict__ Jw, int* __restrict__ flag) {
    if (threadIdx.x != 0 || blockIdx.x != 0) return;
    int votes = 0;
    for (int i = 0; i < 8; ++i) {
        unsigned int w = Jw[i];
        unsigned int ex = (w >> 23) & 0xFFu;
        if ((w >> 31) == 0u && ex >= 100u && ex <= 126u) votes++;
    }
    *flag = (votes >= 6) ? 1 : 0;
}

struct CvtArgs {
    const void* src[16];
    float* dst[16];
    int n[16];
};
__global__ void k_cvt_all(CvtArgs a, const int* __restrict__ flag) {
    int which = blockIdx.y;
    int i = blockIdx.x * 256 + threadIdx.x;
    if (i >= a.n[which]) return;
    float v;
    if (*flag) v = ((const float*)a.src[which])[i];
    else       v = bf2f(((const ushort_t*)a.src[which])[i]);
    a.dst[which][i] = v;
}

struct TrArgs {
    const float* src[6];
    ushort_t* dst[6];
    int K[6];
    int Nc[6];
    int perm[6];
};
// perm=1 (W3 transposes): fold the k_ffn(BM=64) H-tile packing permutation into
// the k index (k is a summation index of hid@W3 — any consistent reorder is
// exact). H row holds halfword h at logical hid-col col(h) = (h&32) +
// ((h>>1)&15) + (h&1)*16; stored index sigma must satisfy col(sigma)=kk:
//   sigma = (kk&32) + 2*(kk&15) + ((kk>>4)&1)
__global__ void k_tr_all(TrArgs a) {
    int which = blockIdx.y;
    int idx = blockIdx.x * 256 + threadIdx.x;
    int K = a.K[which], Nc = a.Nc[which];
    if (idx >= K * Nc) return;
    int k = idx / Nc, n = idx - k * Nc;
    int kd = k;
    if (a.perm[which]) {
        int kk = k & 63;
        kd = (k & ~63) | ((kk & 32) + 2 * (kk & 15) + ((kk >> 4) & 1));
    }
    a.dst[which][n * K + kd] = f2bf(a.src[which][idx]);
}

// ---------------- CSR build ----------------
__global__ void k_deg(const int* __restrict__ ei, int* __restrict__ deg) {
    int e = blockIdx.x * 256 + threadIdx.x;
    if (e >= EP) return;
    int d = (e < NE) ? ei[NE + e] : (e - NE);
    atomicAdd(&deg[d], 1);
}

__global__ void k_part(const int* __restrict__ deg, int* __restrict__ part) {
    __shared__ int sm[256];
    int i = blockIdx.x * 256 + threadIdx.x;
    int v = (i < NN) ? deg[i] : 0;
    sm[threadIdx.x] = v;
    __syncthreads();
    for (int off = 128; off > 0; off >>= 1) {
        if (threadIdx.x < off) sm[threadIdx.x] += sm[threadIdx.x + off];
        __syncthreads();
    }
    if (threadIdx.x == 0) part[blockIdx.x] = sm[0];
}

__global__ void k_scan2(const int* __restrict__ part, int* __restrict__ poff,
                        int* __restrict__ rowp) {
    __shared__ int sm[256];
    int t = threadIdx.x;
    int v = (t < NB_SCAN) ? part[t] : 0;
    sm[t] = v;
    __syncthreads();
    int incl = v;
    for (int off = 1; off < 256; off <<= 1) {
        int u = (t >= off) ? sm[t - off] : 0;
        __syncthreads();
        incl += u;
        sm[t] = incl;
        __syncthreads();
    }
    if (t < NB_SCAN) poff[t] = incl - v;
    if (t == 255) rowp[NN] = sm[255];
}

// rowp + dinv + fill-init fused
__global__ void k_rowp(const int* __restrict__ deg, const int* __restrict__ poff,
                       int* __restrict__ rowp, float* __restrict__ dinv,
                       int* __restrict__ fill) {
    __shared__ int sm[256];
    int i = blockIdx.x * 256 + threadIdx.x;
    int t = threadIdx.x;
    int v = (i < NN) ? deg[i] : 0;
    sm[t] = v;
    __syncthreads();
    int incl = v;
    for (int off = 1; off < 256; off <<= 1) {
        int u = (t >= off) ? sm[t - off] : 0;
        __syncthreads();
        incl += u;
        sm[t] = incl;
        __syncthreads();
    }
    if (i < NN) {
        int rp = poff[blockIdx.x] + incl - v;
        rowp[i] = rp;
        fill[i] = rp;
        dinv[i] = rsqrtf(fmaxf((float)v, 1.0f));
    }
}

__global__ void k_fill(const int* __restrict__ ei, int* __restrict__ fillpos,
                       ushort_t* __restrict__ col) {
    int e = blockIdx.x * 256 + threadIdx.x;
    if (e >= EP) return;
    int s, d;
    if (e < NE) { s = ei[e]; d = ei[NE + e]; } else { s = d = e - NE; }
    int pos = atomicAdd(&fillpos[d], 1);
    col[pos] = (ushort_t)s;
}

// ---------------- elementwise ----------------
__global__ void k_lin0(const float* __restrict__ x, const float* __restrict__ J,
                       const float* __restrict__ w, const float* __restrict__ b,
                       ushort_t* __restrict__ hB) {
    int idx = blockIdx.x * 256 + threadIdx.x;
    if (idx >= NN * DEMB) return;
    int n = idx >> 7, d = idx & 127;
    float v = x[n * 2] * w[d] + x[n * 2 + 1] * w[DEMB + d] + J[n] * w[2 * DEMB + d] + b[d];
    hB[idx] = f2bf(v);
}

__global__ void k_att(const unsigned int* __restrict__ xlB, const float* __restrict__ asrc,
                      const float* __restrict__ adst, float* __restrict__ a_s,
                      float* __restrict__ a_d) {
    int idx = blockIdx.x * 256 + threadIdx.x;
    if (idx >= NN * 8) return;
    int n = idx >> 3, hh = idx & 7;
    const unsigned int* row = xlB + (size_t)n * 64 + hh * 8;
    float s = 0.f, d = 0.f;
#pragma unroll
    for (int c = 0; c < 8; ++c) {
        unsigned int w = row[c];
        float v0 = lo16(w), v1 = hi16(w);
        s += v0 * asrc[hh * 16 + 2 * c] + v1 * asrc[hh * 16 + 2 * c + 1];
        d += v0 * adst[hh * 16 + 2 * c] + v1 * adst[hh * 16 + 2 * c + 1];
    }
    a_s[idx] = s;
    a_d[idx] = d;
}

// BN1 stats pass: recompute z = h + g@w1 (h from bf16), accumulate stats only
__global__ __launch_bounds__(256) void k_z1s(const ushort_t* __restrict__ hB,
                                             const float* __restrict__ g,
                                             const float* __restrict__ w1,
                                             float* __restrict__ stats) {
    int d = threadIdx.x & 127;
    int rstart = blockIdx.x * 2 + (threadIdx.x >> 7);
    int stride = gridDim.x * 2;
    float s1 = 0.f, s2 = 0.f;
    for (int r = rstart; r < NN; r += stride) {
        const float* gr = g + r * 16;
        float s = bf2f(hB[(size_t)r * DEMB + d]);
#pragma unroll
        for (int c = 0; c < 16; ++c) s += gr[c] * w1[c * DEMB + d];
        s1 += s;
        s2 += s * s;
    }
    __shared__ float b1[256], b2[256];
    b1[threadIdx.x] = s1;
    b2[threadIdx.x] = s2;
    __syncthreads();
    if (threadIdx.x < 128) {
        atomicAdd(&stats[threadIdx.x], b1[threadIdx.x] + b1[threadIdx.x + 128]);
        atomicAdd(&stats[128 + threadIdx.x], b2[threadIdx.x] + b2[threadIdx.x + 128]);
    }
}

// BN1 apply with recompute (h from bf16); out h1 bf16 only
__global__ void k_bnapply1(const ushort_t* __restrict__ hB, const float* __restrict__ g,
                           const float* __restrict__ w1, const float* __restrict__ stats,
                           const float* __restrict__ gam, const float* __restrict__ bet,
                           ushort_t* __restrict__ outB) {
    int idx = blockIdx.x * 256 + threadIdx.x;
    if (idx >= NN * DEMB) return;
    int n = idx >> 7, d = idx & 127;
    float s = bf2f(hB[idx]);
    const float* gr = g + n * 16;
#pragma unroll
    for (int c = 0; c < 16; ++c) s += gr[c] * w1[c * DEMB + d];
    const float invN = 1.0f / (float)NN;
    float mu = stats[d] * invN;
    float var = stats[128 + d] * invN - mu * mu;
    float rs = rsqrtf(fmaxf(var, 0.f) + 1e-5f);
    float v = gam[d] * (s - mu) * rs + bet[d];
    outB[idx] = f2bf(v);
}

// BN2 apply (layer 0): z from bf16; out hB bf16
__global__ void k_bnapply(const ushort_t* __restrict__ zB, const float* __restrict__ stats,
                          const float* __restrict__ gam, const float* __restrict__ bet,
                          ushort_t* __restrict__ outB) {
    int idx = blockIdx.x * 256 + threadIdx.x;
    if (idx >= NN * DEMB) return;
    int d = idx & 127;
    const float invN = 1.0f / (float)NN;
    float mu = stats[d] * invN;
    float var = stats[128 + d] * invN - mu * mu;
    float rs = rsqrtf(fmaxf(var, 0.f) + 1e-5f);
    float v = gam[d] * (bf2f(zB[idx]) - mu) * rs + bet[d];
    outB[idx] = f2bf(v);
}

// BN2 apply (layer 1, final): z from bf16; emit APPNP inputs in SLAB-MAJOR
// layout [4 slabs][NN][16 u32] (slab q = dims [32q,32q+32))
__global__ void k_bnapply_fin(const unsigned int* __restrict__ zB, const float* __restrict__ stats,
                              const float* __restrict__ gam, const float* __restrict__ bet,
                              const float* __restrict__ dinv,
                              unsigned int* __restrict__ hs, unsigned int* __restrict__ h0p) {
    int idx = blockIdx.x * 256 + threadIdx.x;
    if (idx >= NN * 64) return;
    int n = idx >> 6, j = idx & 63;
    int d0 = j * 2;
    const float invN = 1.0f / (float)NN;
    unsigned int zw = zB[idx];
    float z0 = lo16(zw), z1 = hi16(zw);
    float mu0 = stats[d0] * invN, mu1 = stats[d0 + 1] * invN;
    float v0 = stats[128 + d0] * invN - mu0 * mu0;
    float v1 = stats[128 + d0 + 1] * invN - mu1 * mu1;
    float rs0 = rsqrtf(fmaxf(v0, 0.f) + 1e-5f);
    float rs1 = rsqrtf(fmaxf(v1, 0.f) + 1e-5f);
    float a = gam[d0] * (z0 - mu0) * rs0 + bet[d0];
    float b = gam[d0 + 1] * (z1 - mu1) * rs1 + bet[d0 + 1];
    float di = dinv[n];
    int q = j >> 4, dd = j & 15;
    size_t o = (size_t)q * NN * 16 + (size_t)n * 16 + dd;
    hs[o] = pack2(di * a, di * b);
    h0p[o] = pack2(a, b);
}

// ---------------- GAT: single-pass softmax-aggregate (wave per node) ----------------
__global__ __launch_bounds__(256) void k_gat(const int* __restrict__ rowp,
                                             const ushort_t* __restrict__ col,
                                             const float* __restrict__ a_s, const float* __restrict__ a_d,
                                             const unsigned int* __restrict__ xlB, float* __restrict__ g) {
    int wid = (blockIdx.x * 256 + threadIdx.x) >> 6;
    int lane = threadIdx.x & 63;
    if (wid >= NN) return;
    int p0 = rowp[wid], p1 = rowp[wid + 1];
    int hh = lane >> 3;
    float ad2 = a_d[wid * 8 + hh];
    float acc0 = 0.f, acc1 = 0.f, s = 0.f;
    int p = p0;
    while (p < p1) {
        int cnt = p1 - p;
        if (cnt > 64) cnt = 64;
        int pl = p + lane;
        int jv = (int)col[pl < p1 ? pl : (p1 - 1)];
        int i = 0;
        for (; i + 8 <= cnt; i += 8) {
            int j0 = __shfl(jv, i),     j1 = __shfl(jv, i + 1);
            int j2 = __shfl(jv, i + 2), j3 = __shfl(jv, i + 3);
            int j4 = __shfl(jv, i + 4), j5 = __shfl(jv, i + 5);
            int j6 = __shfl(jv, i + 6), j7 = __shfl(jv, i + 7);
            float e0 = a_s[j0 * 8 + hh] + ad2, e1 = a_s[j1 * 8 + hh] + ad2;
            float e2 = a_s[j2 * 8 + hh] + ad2, e3 = a_s[j3 * 8 + hh] + ad2;
            float e4 = a_s[j4 * 8 + hh] + ad2, e5 = a_s[j5 * 8 + hh] + ad2;
            float e6 = a_s[j6 * 8 + hh] + ad2, e7 = a_s[j7 * 8 + hh] + ad2;
            unsigned int w0 = xlB[j0 * 64 + lane], w1 = xlB[j1 * 64 + lane];
            unsigned int w2 = xlB[j2 * 64 + lane], w3 = xlB[j3 * 64 + lane];
            unsigned int w4 = xlB[j4 * 64 + lane], w5 = xlB[j5 * 64 + lane];
            unsigned int w6 = xlB[j6 * 64 + lane], w7 = xlB[j7 * 64 + lane];
            e0 = e0 > 0.f ? e0 : 0.2f * e0;  e1 = e1 > 0.f ? e1 : 0.2f * e1;
            e2 = e2 > 0.f ? e2 : 0.2f * e2;  e3 = e3 > 0.f ? e3 : 0.2f * e3;
            e4 = e4 > 0.f ? e4 : 0.2f * e4;  e5 = e5 > 0.f ? e5 : 0.2f * e5;
            e6 = e6 > 0.f ? e6 : 0.2f * e6;  e7 = e7 > 0.f ? e7 : 0.2f * e7;
            float al0 = __expf(e0), al1 = __expf(e1), al2 = __expf(e2), al3 = __expf(e3);
            float al4 = __expf(e4), al5 = __expf(e5), al6 = __expf(e6), al7 = __expf(e7);
            s += al0 + al1 + al2 + al3 + al4 + al5 + al6 + al7;
            acc0 += al0 * lo16(w0) + al1 * lo16(w1) + al2 * lo16(w2) + al3 * lo16(w3) +
                    al4 * lo16(w4) + al5 * lo16(w5) + al6 * lo16(w6) + al7 * lo16(w7);
            acc1 += al0 * hi16(w0) + al1 * hi16(w1) + al2 * hi16(w2) + al3 * hi16(w3) +
                    al4 * hi16(w4) + al5 * hi16(w5) + al6 * hi16(w6) + al7 * hi16(w7);
        }
        for (; i < cnt; ++i) {
            int j = __shfl(jv, i);
            float e = a_s[j * 8 + hh] + ad2;
            e = e > 0.f ? e : 0.2f * e;
            float al = __expf(e);
            unsigned int w = xlB[j * 64 + lane];
            s += al;
            acc0 += al * lo16(w);
            acc1 += al * hi16(w);
        }
        p += cnt;
    }
    float inv = 1.f / s;
    acc0 *= inv;
    acc1 *= inv;
    acc0 += __shfl_xor(acc0, 8);  acc1 += __shfl_xor(acc1, 8);
    acc0 += __shfl_xor(acc0, 16); acc1 += __shfl_xor(acc1, 16);
    acc0 += __shfl_xor(acc0, 32); acc1 += __shfl_xor(acc1, 32);
    if (lane < 8) ((float2*)g)[wid * 8 + lane] = make_float2(acc0, acc1);
}

// ---------------- APPNP step: slabbed, wave = 4 nodes x 1 slab ----------------
// hs/h0p layout [4 slabs][NN][16 u32]; slab q holds dims [32q,32q+32).
// Lanes = 4 node-groups x 16 dims. Each 16-lane group owns one node: stages 16
// edge indices per col load, then 8 independent predicated 64B gathers in
// flight (4 segments per wave-load across groups). One lane accumulates ALL
// edges for its dim -> no cross-lane reduce, all 64 lanes write.
// 50000 waves total (same as the round-4 unslabbed kernel) but gathers are
// L2-resident: block->slab map (b&7)>>1 rides the XCD round-robin so each XCD
// touches one 3.2MB slab (round-5: FETCH 45.5 vs 90.8 MB/step).
// Grid 12504 = 8 x 1563: s=(b&7)>>1, g=2*(b>>3)+(b&1) in [0,3126); g*16+15 >= NN guarded.
__global__ __launch_bounds__(256) void k_appnp(const int* __restrict__ rowp,
                                               const ushort_t* __restrict__ col,
                                               const float* __restrict__ dinv,
                                               const unsigned int* __restrict__ hs,
                                               const unsigned int* __restrict__ h0p,
                                               unsigned int* __restrict__ hs_out,
                                               const float* __restrict__ Jf,
                                               const int* __restrict__ flag,
                                               void* __restrict__ out, int writeOut) {
    int b = blockIdx.x;
    int w = threadIdx.x >> 6, lane = threadIdx.x & 63;
    int s = (b & 7) >> 1;                 // slab (2 XCDs per slab)
    int g = ((b >> 3) << 1) + (b & 1);    // group within slab [0,3126)
    int ns = lane >> 4, d = lane & 15;
    int n = g * 16 + w * 4 + ns;          // this group's node
    int valid = (n < NN);
    int nc = valid ? n : (NN - 1);
    int p0 = rowp[nc], p1 = rowp[nc + 1];
    const unsigned int* hsq = hs + (size_t)s * NN * 16;
    unsigned int hw = h0p[(size_t)s * NN * 16 + (size_t)nc * 16 + d];  // hoisted
    float di = dinv[nc];
    int base = ns << 4;
    float a0 = 0.f, a1 = 0.f;
    int p = p0;
    while (p < p1) {                      // group-uniform trip count
        int cnt = p1 - p;
        if (cnt > 16) cnt = 16;
        int pl = p + d;
        int jv = (int)col[pl < p1 ? pl : (p1 - 1)];
        int lim = cnt - 1;
        for (int k = 0; k < cnt; k += 8) {
            int q0 = k,     q1 = k + 1, q2 = k + 2, q3 = k + 3;
            int q4 = k + 4, q5 = k + 5, q6 = k + 6, q7 = k + 7;
            int j0 = __shfl(jv, base + (q0 < lim ? q0 : lim));
            int j1 = __shfl(jv, base + (q1 < lim ? q1 : lim));
            int j2 = __shfl(jv, base + (q2 < lim ? q2 : lim));
            int j3 = __shfl(jv, base + (q3 < lim ? q3 : lim));
            int j4 = __shfl(jv, base + (q4 < lim ? q4 : lim));
            int j5 = __shfl(jv, base + (q5 < lim ? q5 : lim));
            int j6 = __shfl(jv, base + (q6 < lim ? q6 : lim));
            int j7 = __shfl(jv, base + (q7 < lim ? q7 : lim));
            unsigned int w0 = hsq[j0 * 16 + d], w1 = hsq[j1 * 16 + d];
            unsigned int w2 = hsq[j2 * 16 + d], w3 = hsq[j3 * 16 + d];
            unsigned int w4 = hsq[j4 * 16 + d], w5 = hsq[j5 * 16 + d];
            unsigned int w6 = hsq[j6 * 16 + d], w7 = hsq[j7 * 16 + d];
            a0 += ((q0 <= lim) ? lo16(w0) : 0.f) + ((q1 <= lim) ? lo16(w1) : 0.f) +
                  ((q2 <= lim) ? lo16(w2) : 0.f) + ((q3 <= lim) ? lo16(w3) : 0.f) +
                  ((q4 <= lim) ? lo16(w4) : 0.f) + ((q5 <= lim) ? lo16(w5) : 0.f) +
                  ((q6 <= lim) ? lo16(w6) : 0.f) + ((q7 <= lim) ? lo16(w7) : 0.f);
            a1 += ((q0 <= lim) ? hi16(w0) : 0.f) + ((q1 <= lim) ? hi16(w1) : 0.f) +
                  ((q2 <= lim) ? hi16(w2) : 0.f) + ((q3 <= lim) ? hi16(w3) : 0.f) +
                  ((q4 <= lim) ? hi16(w4) : 0.f) + ((q5 <= lim) ? hi16(w5) : 0.f) +
                  ((q6 <= lim) ? hi16(w6) : 0.f) + ((q7 <= lim) ? hi16(w7) : 0.f);
        }
        p += cnt;
    }
    float n0 = 0.9f * di * a0 + 0.1f * lo16(hw);
    float n1 = 0.9f * di * a1 + 0.1f * hi16(hw);
    if (valid) {
        if (!writeOut) {
            hs_out[(size_t)s * NN * 16 + (size_t)n * 16 + d] = pack2(di * n0, di * n1);
        } else {
            size_t obase = (size_t)n * 129 + s * 32 + 2 * d;
            if (*flag) {
                float* o = (float*)out;
                o[obase] = n0;
                o[obase + 1] = n1;
                if (s == 0 && d == 0) o[(size_t)n * 129 + 128] = Jf[n];
            } else {
                ushort_t* o = (ushort_t*)out;
                o[obase] = f2bf(n0);
                o[obase + 1] = f2bf(n1);
                if (s == 0 && d == 0) o[(size_t)n * 129 + 128] = f2bf(Jf[n]);
            }
        }
    }
}

// ---------------- 64x128-tile MFMA GEMM, double-buffered ----------
// MODE 3: outB = bf16(acc)   (used for xl = h @ gat_w)
template <int MODE>
__global__ __launch_bounds__(256) void k_gemm64(const ushort_t* __restrict__ A,
                                                const ushort_t* __restrict__ Bt,
                                                int M, int K, int Nc,
                                                const float* __restrict__ bias,
                                                const ushort_t* __restrict__ res,
                                                ushort_t* __restrict__ outB,
                                                float* __restrict__ stats) {
    __shared__ __align__(16) ushort_t lsA[2][64 * 32];
    __shared__ __align__(16) ushort_t lsB[2][128 * 32];
    int t = threadIdx.x;
    int m0 = blockIdx.x * 64;
    int n0 = blockIdx.y * 128;
    int w = t >> 6, lane = t & 63;
    int row16 = lane & 15, quad = lane >> 4;
    int nbase = w * 32;
    float4_t acc[8];
#pragma unroll
    for (int i = 0; i < 8; ++i) acc[i] = (float4_t){0.f, 0.f, 0.f, 0.f};
    int lrow = lane >> 2;
    int lcol = (lane & 3) * 8;
    const ushort_t* gA  = A  + (size_t)(m0 + w * 16 + lrow) * K + lcol;
    const ushort_t* gB0 = Bt + (size_t)(n0 + w * 32 + lrow) * K + lcol;
    const ushort_t* gB1 = Bt + (size_t)(n0 + w * 32 + 16 + lrow) * K + lcol;
    ushort_t* dA  = &lsA[0][0] + (w * 16) * 32;
    ushort_t* dB0 = &lsB[0][0] + (w * 32) * 32;
    ushort_t* dB1 = &lsB[0][0] + (w * 32 + 16) * 32;
    const int bufStrideA = 64 * 32, bufStrideB = 128 * 32;
    const int nK = K >> 5;
    gl_lds16(gA, dA);
    gl_lds16(gB0, dB0);
    gl_lds16(gB1, dB1);
    for (int kb = 0; kb < nK; ++kb) {
        __syncthreads();
        int nb = kb + 1;
        if (nb < nK) {
            int b = nb & 1;
            int k0 = nb << 5;
            gl_lds16(gA + k0, dA + b * bufStrideA);
            gl_lds16(gB0 + k0, dB0 + b * bufStrideB);
            gl_lds16(gB1 + k0, dB1 + b * bufStrideB);
        }
        const ushort_t* la = &lsA[kb & 1][0];
        const ushort_t* lb = &lsB[kb & 1][0];
        short8_t afr[4], bfr[2];
#pragma unroll
        for (int i = 0; i < 4; ++i)
            afr[i] = *(const short8_t*)(la + (i * 16 + row16) * 32 + quad * 8);
#pragma unroll
        for (int i = 0; i < 2; ++i)
            bfr[i] = *(const short8_t*)(lb + (nbase + i * 16 + row16) * 32 + quad * 8);
#pragma unroll
        for (int mt = 0; mt < 4; ++mt)
#pragma unroll
            for (int nt = 0; nt < 2; ++nt)
                acc[mt * 2 + nt] = __builtin_amdgcn_mfma_f32_16x16x32_bf16(
                    afr[mt], bfr[nt], acc[mt * 2 + nt], 0, 0, 0);
    }
#pragma unroll
    for (int mt = 0; mt < 4; ++mt) {
#pragma unroll
        for (int nt = 0; nt < 2; ++nt) {
            int cc = n0 + nbase + nt * 16 + row16;
#pragma unroll
            for (int r = 0; r < 4; ++r) {
                int rr = m0 + mt * 16 + quad * 4 + r;
                if (rr < M) {
                    outB[(size_t)rr * Nc + cc] = f2bf(acc[mt * 2 + nt][r]);
                }
            }
        }
    }
}

// ---------------- fused FFN (round-4 BM=64): z = relu(A@W2+b2)@W3 + b3 + res ----
// A:[NP][128] bf16, W2t:[512 n][128 k] bf16, W3t:[128 n][512 k, sigma-permuted].
// LDS = 16K(W2) + 16K(W3) + 16K(A prologue -> H 8K + stats 1K) = 48KB -> 3
// blocks/CU. Waves 2m x 2n; afrA hoisted (32 VGPRs). Two barriers per chunk
// with staggered single-buffer restaging (each stage drained by the NEXT
// barrier's vmcnt(0), one phase before its consumer). Verified 57.2us (round 4);
// BM=32 variant regressed to 75.7us (staging traffic doubles with block count).
__global__ __launch_bounds__(256, 3) void k_ffn(const ushort_t* __restrict__ A,
                                                const ushort_t* __restrict__ W2t,
                                                const ushort_t* __restrict__ W3t,
                                                const float* __restrict__ b2,
                                                const float* __restrict__ b3,
                                                const ushort_t* __restrict__ res,
                                                ushort_t* __restrict__ outB,
                                                float* __restrict__ stats) {
    __shared__ __align__(16) ushort_t sW2[4 * 64 * 32];   // 16KB [kb][64 n][32 k]
    __shared__ __align__(16) ushort_t sW3[2 * 128 * 32];  // 16KB [ks][128 n][32 k]
    __shared__ __align__(16) ushort_t sAH[4 * 2048];      // 16KB A prologue; then H+stats
    int t = threadIdx.x;
    int w = t >> 6, lane = t & 63;
    int wm = w >> 1, wn = w & 1;
    int m0 = blockIdx.x * 64;
    int row16 = lane & 15, quad = lane >> 4;
    int sw = (row16 >> 2) & 3;   // read-side k-group swizzle
    int srow = lane >> 2;        // staging: row within a 16-row issue
    int klin = lane & 3;         // staging: linear k-group this lane fills

    // ---- prologue staging: A tile, W2 chunk 0, W3 chunk 0 ----
#pragma unroll
    for (int i = 0; i < 4; ++i) {
        int row = i * 16 + srow;
        int kc = klin ^ ((row >> 2) & 3);
        gl_lds16(A + (size_t)(m0 + row) * 128 + w * 32 + kc * 8,
                 sAH + w * 2048 + i * 512);
        gl_lds16(W2t + (size_t)row * 128 + w * 32 + kc * 8,
                 sW2 + w * 2048 + i * 512);
        int f = w * 4 + i;
        int ks = f >> 3;
        int n3 = (f & 7) * 16 + srow;
        int kc3 = klin ^ ((n3 >> 2) & 3);
        gl_lds16(W3t + (size_t)n3 * 512 + ks * 32 + kc3 * 8,
                 sW3 + f * 512);
    }
    __syncthreads();

    // hoist A fragments (chunk-invariant): afrA[mt][kb], 32 VGPRs
    short8_t afrA[2][4];
#pragma unroll
    for (int mt = 0; mt < 2; ++mt)
#pragma unroll
        for (int kb = 0; kb < 4; ++kb)
            afrA[mt][kb] = *(const short8_t*)(sAH + kb * 2048 +
                                              (wm * 32 + mt * 16 + row16) * 32 + (quad ^ sw) * 8);
    __syncthreads();   // A region free -> H + stats

    char* Hb = (char*)sAH;             // 8KB H: 64 rows x 128B
    float* s1 = (float*)(Hb + 8192);   // 128 f32
    float* s2 = s1 + 128;
    if (t < 128) { s1[t] = 0.f; s2[t] = 0.f; }

    float4_t accz[2][4];
#pragma unroll
    for (int mt = 0; mt < 2; ++mt)
#pragma unroll
        for (int nt = 0; nt < 4; ++nt) accz[mt][nt] = (float4_t){0.f, 0.f, 0.f, 0.f};

    for (int c = 0; c < 8; ++c) {
        // ---- phase 1: hid_c = relu(A @ W2[:, 64c:64c+64] + b2), n-slice wn ----
        float b20 = b2[c * 64 + wn * 32 + row16];
        float b21 = b2[c * 64 + wn * 32 + 16 + row16];
        float4_t acch[2][2];
#pragma unroll
        for (int mt = 0; mt < 2; ++mt)
#pragma unroll
            for (int nt = 0; nt < 2; ++nt) acch[mt][nt] = (float4_t){0.f, 0.f, 0.f, 0.f};
#pragma unroll
        for (int kb = 0; kb < 4; ++kb) {
            short8_t b0 = *(const short8_t*)(sW2 + kb * 2048 +
                                             (wn * 32 + row16) * 32 + (quad ^ sw) * 8);
            short8_t b1 = *(const short8_t*)(sW2 + kb * 2048 +
                                             (wn * 32 + 16 + row16) * 32 + (quad ^ sw) * 8);
            acch[0][0] = __builtin_amdgcn_mfma_f32_16x16x32_bf16(afrA[0][kb], b0, acch[0][0], 0, 0, 0);
            acch[0][1] = __builtin_amdgcn_mfma_f32_16x16x32_bf16(afrA[0][kb], b1, acch[0][1], 0, 0, 0);
            acch[1][0] = __builtin_amdgcn_mfma_f32_16x16x32_bf16(afrA[1][kb], b0, acch[1][0], 0, 0, 0);
            acch[1][1] = __builtin_amdgcn_mfma_f32_16x16x32_bf16(afrA[1][kb], b1, acch[1][1], 0, 0, 0);
        }
        // relu+bias -> packed H writes (8 x b32 per lane, 2-way banks = free)
#pragma unroll
        for (int mt = 0; mt < 2; ++mt) {
#pragma unroll
            for (int r = 0; r < 4; ++r) {
                int row = wm * 32 + mt * 16 + quad * 4 + r;
                int d = wn * 16 + row16;
                int byteOff = row * 128 + ((((d >> 2) ^ (row & 7))) << 4) + (d & 3) * 4;
                float v0 = acch[mt][0][r] + b20; v0 = v0 > 0.f ? v0 : 0.f;
                float v1 = acch[mt][1][r] + b21; v1 = v1 > 0.f ? v1 : 0.f;
                *(unsigned int*)(Hb + byteOff) = pack2(v0, v1);
            }
        }
        __syncthreads();   // B1: H visible to all waves; W2(c) fully consumed
        if (c < 7) {       // restage W2 (drained by vmcnt(0) at B2)
#pragma unroll
            for (int i = 0; i < 4; ++i) {
                int n = i * 16 + srow;
                int kc = klin ^ ((n >> 2) & 3);
                gl_lds16(W2t + (size_t)((c + 1) * 64 + n) * 128 + w * 32 + kc * 8,
                         sW2 + w * 2048 + i * 512);
            }
        }
        // ---- phase 2: accz += hid_c @ W3[64c:64c+64, :], n-half wn ----
#pragma unroll
        for (int ks = 0; ks < 2; ++ks) {
            short8_t afrH[2];
#pragma unroll
            for (int mt = 0; mt < 2; ++mt)
                afrH[mt] = *(const short8_t*)(Hb + (wm * 32 + mt * 16 + row16) * 128 +
                                              (((ks * 4 + quad) ^ (row16 & 7)) << 4));
#pragma unroll
            for (int nt = 0; nt < 4; ++nt) {
                short8_t bfr = *(const short8_t*)(sW3 + ks * 4096 +
                                                  (wn * 64 + nt * 16 + row16) * 32 + (quad ^ sw) * 8);
                accz[0][nt] = __builtin_amdgcn_mfma_f32_16x16x32_bf16(afrH[0], bfr, accz[0][nt], 0, 0, 0);
                accz[1][nt] = __builtin_amdgcn_mfma_f32_16x16x32_bf16(afrH[1], bfr, accz[1][nt], 0, 0, 0);
            }
        }
        __syncthreads();   // B2: W3(c)+H consumed; W2(c+1) drained here
        if (c < 7) {       // restage W3 (drained by vmcnt(0) at next B1)
#pragma unroll
            for (int i = 0; i < 4; ++i) {
                int f = w * 4 + i;
                int ks = f >> 3;
                int n = (f & 7) * 16 + srow;
                int kc = klin ^ ((n >> 2) & 3);
                gl_lds16(W3t + (size_t)n * 512 + (c + 1) * 64 + ks * 32 + kc * 8,
                         sW3 + f * 512);
            }
        }
    }

    // ---- epilogue: z = accz + b3 + res ; write bf16 + BN stats ----
#pragma unroll
    for (int mt = 0; mt < 2; ++mt) {
#pragma unroll
        for (int nt = 0; nt < 4; ++nt) {
            int cc = wn * 64 + nt * 16 + row16;
            float bv = b3[cc];
            float ls = 0.f, lq = 0.f;
#pragma unroll
            for (int r = 0; r < 4; ++r) {
                int rr = m0 + wm * 32 + mt * 16 + quad * 4 + r;
                if (rr < NN) {
                    float v = accz[mt][nt][r] + bv + bf2f(res[(size_t)rr * 128 + cc]);
                    outB[(size_t)rr * 128 + cc] = f2bf(v);
                    ls += v;
                    lq += v * v;
                }
            }
            atomicAdd(&s1[cc], ls);
            atomicAdd(&s2[cc], lq);
        }
    }
    __syncthreads();
    if (t < 128) {
        atomicAdd(&stats[t], s1[t]);
        atomicAdd(&stats[128 + t], s2[t]);
    }
}

// ---------------- host ----------------
extern "C" void kernel_launch(void* const* d_in, const int* in_sizes, int n_in,
                              void* d_out, int out_size, void* d_ws, size_t ws_size,
                              hipStream_t stream) {
    const int* ei = (const int*)d_in[2];

    char* p = (char*)d_ws;
    auto alloc = [&](size_t bytes) {
        void* r = (void*)p;
        p += (bytes + 255) & ~(size_t)255;
        return r;
    };
    ushort_t* hB    = (ushort_t*)alloc((size_t)NP * DEMB * 2);   // h (padded)
    ushort_t* h1B   = (ushort_t*)alloc((size_t)NP * DEMB * 2);   // h1 (padded)
    ushort_t* xlB   = (ushort_t*)alloc((size_t)NN * DEMB * 2);   // xl, reused as zB
    unsigned int* hsA  = (unsigned int*)alloc((size_t)NN * 64 * 4);
    unsigned int* hsB_ = (unsigned int*)alloc((size_t)NN * 64 * 4);
    unsigned int* h0p  = (unsigned int*)alloc((size_t)NN * 64 * 4);
    float*    asv   = (float*)alloc((size_t)NN * 8 * 4);
    float*    adv   = (float*)alloc((size_t)NN * 8 * 4);
    float*    gv    = (float*)alloc((size_t)NN * 16 * 4);
    float*    dinvv = (float*)alloc((size_t)NN * 4);
    float*    stats = (float*)alloc(4 * 256 * 4);
    int*      deg   = (int*)alloc((size_t)NN * 4);
    int*      rowp  = (int*)alloc((size_t)(NN + 1) * 4);
    int*      fill  = (int*)alloc((size_t)NN * 4);
    ushort_t* colv  = (ushort_t*)alloc((size_t)EP * 2);
    int*      part  = (int*)alloc(NB_SCAN * 4);
    int*      poff  = (int*)alloc(NB_SCAN * 4);
    int*      flag  = (int*)alloc(256);
    ushort_t* wtg   = (ushort_t*)alloc((size_t)2 * 128 * 128 * 2);
    ushort_t* wt2   = (ushort_t*)alloc((size_t)2 * 512 * 128 * 2);
    ushort_t* wt3   = (ushort_t*)alloc((size_t)2 * 128 * 512 * 2);
    float* xf   = (float*)alloc((size_t)NN * 2 * 4);
    float* Jf   = (float*)alloc((size_t)NN * 4);
    float* l0wF = (float*)alloc(384 * 4);
    float* l0bF = (float*)alloc(128 * 4);
    float* gwF  = (float*)alloc(32768 * 4);
    float* asF  = (float*)alloc(256 * 4);
    float* adF  = (float*)alloc(256 * 4);
    float* w1F  = (float*)alloc(4096 * 4);
    float* b1gF = (float*)alloc(256 * 4);
    float* b1bF = (float*)alloc(256 * 4);
    float* w2F  = (float*)alloc(131072 * 4);
    float* b2F  = (float*)alloc(1024 * 4);
    float* w3F  = (float*)alloc(131072 * 4);
    float* b3F  = (float*)alloc(256 * 4);
    float* b2gF = (float*)alloc(256 * 4);
    float* b2bF = (float*)alloc(256 * 4);

    // ---- dtype detect + batched canonicalize ----
    k_detect<<<1, 64, 0, stream>>>((const unsigned int*)d_in[1], flag);
    CvtArgs ca;
    {
        const int srcIdx[16] = {0, 1, 3, 4, 5, 6, 7, 8, 9, 10, 11, 12, 13, 14, 15, 16};
        float* dsts[16] = {xf, Jf, l0wF, l0bF, gwF, asF, adF, w1F, b1gF, b1bF,
                           w2F, b2F, w3F, b3F, b2gF, b2bF};
        const int ns[16] = {NN * 2, NN, 384, 128, 32768, 256, 256, 4096, 256, 256,
                            131072, 1024, 131072, 256, 256, 256};
        for (int i = 0; i < 16; ++i) { ca.src[i] = d_in[srcIdx[i]]; ca.dst[i] = dsts[i]; ca.n[i] = ns[i]; }
    }
    k_cvt_all<<<dim3(cdiv(131072, 256), 16), 256, 0, stream>>>(ca, flag);

    // ---- CSR build ----
    hipMemsetAsync(deg, 0, (size_t)NN * 4, stream);
    hipMemsetAsync(stats, 0, 4 * 256 * 4, stream);
    k_deg<<<cdiv(EP, 256), 256, 0, stream>>>(ei, deg);
    k_part<<<NB_SCAN, 256, 0, stream>>>(deg, part);
    k_scan2<<<1, 256, 0, stream>>>(part, poff, rowp);
    k_rowp<<<NB_SCAN, 256, 0, stream>>>(deg, poff, rowp, dinvv, fill);
    k_fill<<<cdiv(EP, 256), 256, 0, stream>>>(ei, fill, colv);

    // ---- batched weight transposes (W3 gets the sigma k-perm for BM=64 ffn) ----
    TrArgs ta;
    {
        const float* srcs[6] = {gwF, gwF + 16384, w2F, w2F + 65536, w3F, w3F + 65536};
        ushort_t* dsts[6] = {wtg, wtg + 16384, wt2, wt2 + 65536, wt3, wt3 + 65536};
        const int Ks[6] = {128, 128, 128, 128, 512, 512};
        const int Ncs[6] = {128, 128, 512, 512, 128, 128};
        const int perms[6] = {0, 0, 0, 0, 1, 1};
        for (int i = 0; i < 6; ++i) {
            ta.src[i] = srcs[i]; ta.dst[i] = dsts[i]; ta.K[i] = Ks[i]; ta.Nc[i] = Ncs[i];
            ta.perm[i] = perms[i];
        }
    }
    k_tr_all<<<dim3(cdiv(65536, 256), 6), 256, 0, stream>>>(ta);

    // ---- input projection (bf16 h only) ----
    k_lin0<<<cdiv(NN * DEMB, 256), 256, 0, stream>>>(xf, Jf, l0wF, l0bF, hB);

    for (int l = 0; l < 2; ++l) {
        float* st1 = stats + (l * 2 + 0) * 256;
        float* st2 = stats + (l * 2 + 1) * 256;
        ushort_t* zB = xlB;  // reuse xl buffer for z after k_gat is done
        // xl (bf16) = h @ gat_w[l]
        k_gemm64<3><<<dim3(NMT64, 1), 256, 0, stream>>>(hB, wtg + l * 16384, NN, 128, 128,
                                                        nullptr, nullptr, xlB, nullptr);
        k_att<<<cdiv(NN * 8, 256), 256, 0, stream>>>((const unsigned int*)xlB, asF + l * 128,
                                                     adF + l * 128, asv, adv);
        k_gat<<<cdiv(NN * 64, 256), 256, 0, stream>>>(rowp, colv, asv, adv,
                                                      (const unsigned int*)xlB, gv);
        k_z1s<<<512, 256, 0, stream>>>(hB, gv, w1F + l * 2048, st1);
        k_bnapply1<<<cdiv(NN * DEMB, 256), 256, 0, stream>>>(hB, gv, w1F + l * 2048, st1,
                                                             b1gF + l * 128, b1bF + l * 128,
                                                             h1B);
        // fused FFN: z = relu(h1@W2+b2)@W3 + b3 + h1, + BN2 stats
        k_ffn<<<NMT64, 256, 0, stream>>>(h1B, wt2 + l * 65536, wt3 + l * 65536,
                                         b2F + l * 512, b3F + l * 128, h1B, zB, st2);
        if (l == 0) {
            k_bnapply<<<cdiv(NN * DEMB, 256), 256, 0, stream>>>(zB, st2, b2gF, b2bF, hB);
        } else {
            k_bnapply_fin<<<cdiv(NN * 64, 256), 256, 0, stream>>>((const unsigned int*)zB, st2,
                                                                  b2gF + 128, b2bF + 128,
                                                                  dinvv, hsA, h0p);
        }
    }

    // ---- APPNP: 10 steps (slabbed, 4 nodes/wave); last writes d_out ----
    unsigned int* pin = hsA;
    unsigned int* pout = hsB_;
    for (int k = 0; k < 10; ++k) {
        int last = (k == 9) ? 1 : 0;
        k_appnp<<<12504, 256, 0, stream>>>(rowp, colv, dinvv, pin, h0p, pout,
                                           Jf, flag, d_out, last);
        unsigned int* tmp = pout;
        pout = pin;
        pin = tmp;
    }
}

// Round 8
// 823.413 us; speedup vs baseline: 1.6012x; 1.0855x over previous
//
#include <hip/hip_runtime.h>

#define NN 50000
#define NN1 50001  // +1 sentinel row (zero) for padded-CSR gathers
#define NP 50048   // padded rows for global_load_lds tail reads
#define NMT64 782  // cdiv(NN,64)
#define NE 800000
#define EP (NE + NN)
#define EPP_MAX (EP + 7 * NN + 64)  // padded CSR upper bound + shfl slack
#define DEMB 128
#define DHID 512
#define NB_SCAN 196  // cdiv(NN,256)

typedef unsigned short ushort_t;
typedef __attribute__((ext_vector_type(8))) short short8_t;
typedef __attribute__((ext_vector_type(4))) float float4_t;

__device__ __forceinline__ float bf2f(ushort_t u) {
    return __uint_as_float(((unsigned int)u) << 16);
}
__device__ __forceinline__ ushort_t f2bf(float f) {
    unsigned int x = __float_as_uint(f);
    x += 0x7fffu + ((x >> 16) & 1u);
    return (ushort_t)(x >> 16);
}
__device__ __forceinline__ float lo16(unsigned int w) { return __uint_as_float(w << 16); }
__device__ __forceinline__ float hi16(unsigned int w) { return __uint_as_float(w & 0xffff0000u); }
__device__ __forceinline__ unsigned int pack2(float a, float b) {
    return (unsigned int)f2bf(a) | ((unsigned int)f2bf(b) << 16);
}
__device__ __forceinline__ void gl_lds16(const ushort_t* g, ushort_t* l) {
    __builtin_amdgcn_global_load_lds(
        (const __attribute__((address_space(1))) void*)g,
        (__attribute__((address_space(3))) void*)l, 16, 0, 0);
}
static inline int cdiv(int a, int b) { return (a + b - 1) / b; }

// ---------------- dtype detect + batched convert ----------------
__global__ void k_detect(const unsigned int* __restrict__ Jw, int* __restrict__ flag) {
    if (threadIdx.x != 0 || blockIdx.x != 0) return;
    int votes = 0;
    for (int i = 0; i < 8; ++i) {
        unsigned int w = Jw[i];
        unsigned int ex = (w >> 23) & 0xFFu;
        if ((w >> 31) == 0u && ex >= 100u && ex <= 126u) votes++;
    }
    *flag = (votes >= 6) ? 1 : 0;
}

struct CvtArgs {
    const void* src[16];
    float* dst[16];
    int n[16];
};
__global__ void k_cvt_all(CvtArgs a, const int* __restrict__ flag) {
    int which = blockIdx.y;
    int i = blockIdx.x * 256 + threadIdx.x;
    if (i >= a.n[which]) return;
    float v;
    if (*flag) v = ((const float*)a.src[which])[i];
    else       v = bf2f(((const ushort_t*)a.src[which])[i]);
    a.dst[which][i] = v;
}

struct TrArgs {
    const float* src[6];
    ushort_t* dst[6];
    int K[6];
    int Nc[6];
    int perm[6];
};
// perm=1 (W3 transposes): fold the k_ffn(BM=64) H-tile packing permutation into
// the k index (k is a summation index of hid@W3 — any consistent reorder is
// exact). H row holds halfword h at logical hid-col col(h) = (h&32) +
// ((h>>1)&15) + (h&1)*16; stored index sigma must satisfy col(sigma)=kk:
//   sigma = (kk&32) + 2*(kk&15) + ((kk>>4)&1)
__global__ void k_tr_all(TrArgs a) {
    int which = blockIdx.y;
    int idx = blockIdx.x * 256 + threadIdx.x;
    int K = a.K[which], Nc = a.Nc[which];
    if (idx >= K * Nc) return;
    int k = idx / Nc, n = idx - k * Nc;
    int kd = k;
    if (a.perm[which]) {
        int kk = k & 63;
        kd = (k & ~63) | ((kk & 32) + 2 * (kk & 15) + ((kk >> 4) & 1));
    }
    a.dst[which][n * K + kd] = f2bf(a.src[which][idx]);
}

// ---------------- CSR build (rows PADDED to multiples of 8 with sentinel NN) ----
__global__ void k_deg(const int* __restrict__ ei, int* __restrict__ deg) {
    int e = blockIdx.x * 256 + threadIdx.x;
    if (e >= EP) return;
    int d = (e < NE) ? ei[NE + e] : (e - NE);
    atomicAdd(&deg[d], 1);
}

__global__ void k_part(const int* __restrict__ deg, int* __restrict__ part) {
    __shared__ int sm[256];
    int i = blockIdx.x * 256 + threadIdx.x;
    int v = (i < NN) ? deg[i] : 0;
    v = (v + 7) & ~7;   // padded degree
    sm[threadIdx.x] = v;
    __syncthreads();
    for (int off = 128; off > 0; off >>= 1) {
        if (threadIdx.x < off) sm[threadIdx.x] += sm[threadIdx.x + off];
        __syncthreads();
    }
    if (threadIdx.x == 0) part[blockIdx.x] = sm[0];
}

__global__ void k_scan2(const int* __restrict__ part, int* __restrict__ poff,
                        int* __restrict__ rowp) {
    __shared__ int sm[256];
    int t = threadIdx.x;
    int v = (t < NB_SCAN) ? part[t] : 0;
    sm[t] = v;
    __syncthreads();
    int incl = v;
    for (int off = 1; off < 256; off <<= 1) {
        int u = (t >= off) ? sm[t - off] : 0;
        __syncthreads();
        incl += u;
        sm[t] = incl;
        __syncthreads();
    }
    if (t < NB_SCAN) poff[t] = incl - v;
    if (t == 255) rowp[NN] = sm[255];
}

// rowp (padded) + dinv (real degree) + fill-init fused
__global__ void k_rowp(const int* __restrict__ deg, const int* __restrict__ poff,
                       int* __restrict__ rowp, float* __restrict__ dinv,
                       int* __restrict__ fill) {
    __shared__ int sm[256];
    int i = blockIdx.x * 256 + threadIdx.x;
    int t = threadIdx.x;
    int rv = (i < NN) ? deg[i] : 0;
    int v = (rv + 7) & ~7;   // padded degree
    sm[t] = v;
    __syncthreads();
    int incl = v;
    for (int off = 1; off < 256; off <<= 1) {
        int u = (t >= off) ? sm[t - off] : 0;
        __syncthreads();
        incl += u;
        sm[t] = incl;
        __syncthreads();
    }
    if (i < NN) {
        int rp = poff[blockIdx.x] + incl - v;
        rowp[i] = rp;
        fill[i] = rp;
        dinv[i] = rsqrtf(fmaxf((float)rv, 1.0f));
    }
}

__global__ void k_fill(const int* __restrict__ ei, int* __restrict__ fillpos,
                       ushort_t* __restrict__ col) {
    int e = blockIdx.x * 256 + threadIdx.x;
    if (e >= EP) return;
    int s, d;
    if (e < NE) { s = ei[e]; d = ei[NE + e]; } else { s = d = e - NE; }
    int pos = atomicAdd(&fillpos[d], 1);
    col[pos] = (ushort_t)s;
}

// fill padding slots [fill[n], rowp[n+1]) with sentinel NN (<=7 per node)
__global__ void k_pad(const int* __restrict__ fillpos, const int* __restrict__ rowp,
                      ushort_t* __restrict__ col) {
    int n = blockIdx.x * 256 + threadIdx.x;
    if (n >= NN) return;
    int p = fillpos[n], p1 = rowp[n + 1];
    for (; p < p1; ++p) col[p] = (ushort_t)NN;
}

// zero the sentinel rows of hsA/hsB_ (slab stride NN1); h0p sentinel never read
__global__ void k_zsent(unsigned int* __restrict__ a, unsigned int* __restrict__ b) {
    int t = threadIdx.x;
    if (t >= 64) return;
    int s = t >> 4, d = t & 15;
    size_t o = (size_t)s * NN1 * 16 + (size_t)NN * 16 + d;
    a[o] = 0;
    b[o] = 0;
}

// ---------------- elementwise ----------------
__global__ void k_lin0(const float* __restrict__ x, const float* __restrict__ J,
                       const float* __restrict__ w, const float* __restrict__ b,
                       ushort_t* __restrict__ hB) {
    int idx = blockIdx.x * 256 + threadIdx.x;
    if (idx >= NN * DEMB) return;
    int n = idx >> 7, d = idx & 127;
    float v = x[n * 2] * w[d] + x[n * 2 + 1] * w[DEMB + d] + J[n] * w[2 * DEMB + d] + b[d];
    hB[idx] = f2bf(v);
}

__global__ void k_att(const unsigned int* __restrict__ xlB, const float* __restrict__ asrc,
                      const float* __restrict__ adst, float* __restrict__ a_s,
                      float* __restrict__ a_d) {
    int idx = blockIdx.x * 256 + threadIdx.x;
    if (idx >= NN * 8) return;
    int n = idx >> 3, hh = idx & 7;
    const unsigned int* row = xlB + (size_t)n * 64 + hh * 8;
    float s = 0.f, d = 0.f;
#pragma unroll
    for (int c = 0; c < 8; ++c) {
        unsigned int w = row[c];
        float v0 = lo16(w), v1 = hi16(w);
        s += v0 * asrc[hh * 16 + 2 * c] + v1 * asrc[hh * 16 + 2 * c + 1];
        d += v0 * adst[hh * 16 + 2 * c] + v1 * adst[hh * 16 + 2 * c + 1];
    }
    a_s[idx] = s;
    a_d[idx] = d;
}

// BN1 stats pass: recompute z = h + g@w1 (h from bf16), accumulate stats only
__global__ __launch_bounds__(256) void k_z1s(const ushort_t* __restrict__ hB,
                                             const float* __restrict__ g,
                                             const float* __restrict__ w1,
                                             float* __restrict__ stats) {
    int d = threadIdx.x & 127;
    int rstart = blockIdx.x * 2 + (threadIdx.x >> 7);
    int stride = gridDim.x * 2;
    float s1 = 0.f, s2 = 0.f;
    for (int r = rstart; r < NN; r += stride) {
        const float* gr = g + r * 16;
        float s = bf2f(hB[(size_t)r * DEMB + d]);
#pragma unroll
        for (int c = 0; c < 16; ++c) s += gr[c] * w1[c * DEMB + d];
        s1 += s;
        s2 += s * s;
    }
    __shared__ float b1[256], b2[256];
    b1[threadIdx.x] = s1;
    b2[threadIdx.x] = s2;
    __syncthreads();
    if (threadIdx.x < 128) {
        atomicAdd(&stats[threadIdx.x], b1[threadIdx.x] + b1[threadIdx.x + 128]);
        atomicAdd(&stats[128 + threadIdx.x], b2[threadIdx.x] + b2[threadIdx.x + 128]);
    }
}

// BN1 apply with recompute (h from bf16); out h1 bf16 only
__global__ void k_bnapply1(const ushort_t* __restrict__ hB, const float* __restrict__ g,
                           const float* __restrict__ w1, const float* __restrict__ stats,
                           const float* __restrict__ gam, const float* __restrict__ bet,
                           ushort_t* __restrict__ outB) {
    int idx = blockIdx.x * 256 + threadIdx.x;
    if (idx >= NN * DEMB) return;
    int n = idx >> 7, d = idx & 127;
    float s = bf2f(hB[idx]);
    const float* gr = g + n * 16;
#pragma unroll
    for (int c = 0; c < 16; ++c) s += gr[c] * w1[c * DEMB + d];
    const float invN = 1.0f / (float)NN;
    float mu = stats[d] * invN;
    float var = stats[128 + d] * invN - mu * mu;
    float rs = rsqrtf(fmaxf(var, 0.f) + 1e-5f);
    float v = gam[d] * (s - mu) * rs + bet[d];
    outB[idx] = f2bf(v);
}

// BN2 apply (layer 0): z from bf16; out hB bf16
__global__ void k_bnapply(const ushort_t* __restrict__ zB, const float* __restrict__ stats,
                          const float* __restrict__ gam, const float* __restrict__ bet,
                          ushort_t* __restrict__ outB) {
    int idx = blockIdx.x * 256 + threadIdx.x;
    if (idx >= NN * DEMB) return;
    int d = idx & 127;
    const float invN = 1.0f / (float)NN;
    float mu = stats[d] * invN;
    float var = stats[128 + d] * invN - mu * mu;
    float rs = rsqrtf(fmaxf(var, 0.f) + 1e-5f);
    float v = gam[d] * (bf2f(zB[idx]) - mu) * rs + bet[d];
    outB[idx] = f2bf(v);
}

// BN2 apply (layer 1, final): z from bf16; emit APPNP inputs in SLAB-MAJOR
// layout [4 slabs][NN1][16 u32] (slab q = dims [32q,32q+32); row NN = sentinel)
__global__ void k_bnapply_fin(const unsigned int* __restrict__ zB, const float* __restrict__ stats,
                              const float* __restrict__ gam, const float* __restrict__ bet,
                              const float* __restrict__ dinv,
                              unsigned int* __restrict__ hs, unsigned int* __restrict__ h0p) {
    int idx = blockIdx.x * 256 + threadIdx.x;
    if (idx >= NN * 64) return;
    int n = idx >> 6, j = idx & 63;
    int d0 = j * 2;
    const float invN = 1.0f / (float)NN;
    unsigned int zw = zB[idx];
    float z0 = lo16(zw), z1 = hi16(zw);
    float mu0 = stats[d0] * invN, mu1 = stats[d0 + 1] * invN;
    float v0 = stats[128 + d0] * invN - mu0 * mu0;
    float v1 = stats[128 + d0 + 1] * invN - mu1 * mu1;
    float rs0 = rsqrtf(fmaxf(v0, 0.f) + 1e-5f);
    float rs1 = rsqrtf(fmaxf(v1, 0.f) + 1e-5f);
    float a = gam[d0] * (z0 - mu0) * rs0 + bet[d0];
    float b = gam[d0 + 1] * (z1 - mu1) * rs1 + bet[d0 + 1];
    float di = dinv[n];
    int q = j >> 4, dd = j & 15;
    size_t o = (size_t)q * NN1 * 16 + (size_t)n * 16 + dd;
    hs[o] = pack2(di * a, di * b);
    h0p[o] = pack2(a, b);
}

// ---------------- GAT: single-pass softmax-aggregate (wave per node) ----------------
// Uses REAL degree extent (p1 = p0 + deg[n]) so CSR padding costs nothing here.
__global__ __launch_bounds__(256) void k_gat(const int* __restrict__ rowp,
                                             const int* __restrict__ deg,
                                             const ushort_t* __restrict__ col,
                                             const float* __restrict__ a_s, const float* __restrict__ a_d,
                                             const unsigned int* __restrict__ xlB, float* __restrict__ g) {
    int wid = (blockIdx.x * 256 + threadIdx.x) >> 6;
    int lane = threadIdx.x & 63;
    if (wid >= NN) return;
    int p0 = rowp[wid], p1 = p0 + deg[wid];
    int hh = lane >> 3;
    float ad2 = a_d[wid * 8 + hh];
    float acc0 = 0.f, acc1 = 0.f, s = 0.f;
    int p = p0;
    while (p < p1) {
        int cnt = p1 - p;
        if (cnt > 64) cnt = 64;
        int pl = p + lane;
        int jv = (int)col[pl < p1 ? pl : (p1 - 1)];
        int i = 0;
        for (; i + 8 <= cnt; i += 8) {
            int j0 = __shfl(jv, i),     j1 = __shfl(jv, i + 1);
            int j2 = __shfl(jv, i + 2), j3 = __shfl(jv, i + 3);
            int j4 = __shfl(jv, i + 4), j5 = __shfl(jv, i + 5);
            int j6 = __shfl(jv, i + 6), j7 = __shfl(jv, i + 7);
            float e0 = a_s[j0 * 8 + hh] + ad2, e1 = a_s[j1 * 8 + hh] + ad2;
            float e2 = a_s[j2 * 8 + hh] + ad2, e3 = a_s[j3 * 8 + hh] + ad2;
            float e4 = a_s[j4 * 8 + hh] + ad2, e5 = a_s[j5 * 8 + hh] + ad2;
            float e6 = a_s[j6 * 8 + hh] + ad2, e7 = a_s[j7 * 8 + hh] + ad2;
            unsigned int w0 = xlB[j0 * 64 + lane], w1 = xlB[j1 * 64 + lane];
            unsigned int w2 = xlB[j2 * 64 + lane], w3 = xlB[j3 * 64 + lane];
            unsigned int w4 = xlB[j4 * 64 + lane], w5 = xlB[j5 * 64 + lane];
            unsigned int w6 = xlB[j6 * 64 + lane], w7 = xlB[j7 * 64 + lane];
            e0 = e0 > 0.f ? e0 : 0.2f * e0;  e1 = e1 > 0.f ? e1 : 0.2f * e1;
            e2 = e2 > 0.f ? e2 : 0.2f * e2;  e3 = e3 > 0.f ? e3 : 0.2f * e3;
            e4 = e4 > 0.f ? e4 : 0.2f * e4;  e5 = e5 > 0.f ? e5 : 0.2f * e5;
            e6 = e6 > 0.f ? e6 : 0.2f * e6;  e7 = e7 > 0.f ? e7 : 0.2f * e7;
            float al0 = __expf(e0), al1 = __expf(e1), al2 = __expf(e2), al3 = __expf(e3);
            float al4 = __expf(e4), al5 = __expf(e5), al6 = __expf(e6), al7 = __expf(e7);
            s += al0 + al1 + al2 + al3 + al4 + al5 + al6 + al7;
            acc0 += al0 * lo16(w0) + al1 * lo16(w1) + al2 * lo16(w2) + al3 * lo16(w3) +
                    al4 * lo16(w4) + al5 * lo16(w5) + al6 * lo16(w6) + al7 * lo16(w7);
            acc1 += al0 * hi16(w0) + al1 * hi16(w1) + al2 * hi16(w2) + al3 * hi16(w3) +
                    al4 * hi16(w4) + al5 * hi16(w5) + al6 * hi16(w6) + al7 * hi16(w7);
        }
        for (; i < cnt; ++i) {
            int j = __shfl(jv, i);
            float e = a_s[j * 8 + hh] + ad2;
            e = e > 0.f ? e : 0.2f * e;
            float al = __expf(e);
            unsigned int w = xlB[j * 64 + lane];
            s += al;
            acc0 += al * lo16(w);
            acc1 += al * hi16(w);
        }
        p += cnt;
    }
    float inv = 1.f / s;
    acc0 *= inv;
    acc1 *= inv;
    acc0 += __shfl_xor(acc0, 8);  acc1 += __shfl_xor(acc1, 8);
    acc0 += __shfl_xor(acc0, 16); acc1 += __shfl_xor(acc1, 16);
    acc0 += __shfl_xor(acc0, 32); acc1 += __shfl_xor(acc1, 32);
    if (lane < 8) ((float2*)g)[wid * 8 + lane] = make_float2(acc0, acc1);
}

// ---------------- APPNP step: slabbed, 4 nodes/wave, predication-free ----------------
// hs/h0p layout [4 slabs][NN1][16 u32]; slab q = dims [32q,32q+32); row NN = 0
// (sentinel). CSR rows padded to multiples of 8 with sentinel NN -> inner loop
// has NO clamps and NO selects (sentinel gathers hit a zero line, add 0.0).
// Lanes = 4 node-groups x 16 dims; one lane accumulates all edges of its dim
// (no cross-lane reduce). 8 independent gathers in flight per chunk.
// Block->slab map (b&7)>>1 rides the XCD round-robin -> 3.2MB slab L2-resident.
__global__ __launch_bounds__(256) void k_appnp(const int* __restrict__ rowp,
                                               const ushort_t* __restrict__ col,
                                               const float* __restrict__ dinv,
                                               const unsigned int* __restrict__ hs,
                                               const unsigned int* __restrict__ h0p,
                                               unsigned int* __restrict__ hs_out,
                                               const float* __restrict__ Jf,
                                               const int* __restrict__ flag,
                                               void* __restrict__ out, int writeOut) {
    int b = blockIdx.x;
    int w = threadIdx.x >> 6, lane = threadIdx.x & 63;
    int s = (b & 7) >> 1;                 // slab (2 XCDs per slab)
    int g = ((b >> 3) << 1) + (b & 1);    // group within slab [0,3126)
    int ns = lane >> 4, d = lane & 15;
    int n = g * 16 + w * 4 + ns;          // this group's node
    int valid = (n < NN);
    int nc = valid ? n : (NN - 1);
    int p0 = rowp[nc], p1 = rowp[nc + 1];  // padded extent (multiple of 8)
    const unsigned int* hsq = hs + (size_t)s * NN1 * 16;
    unsigned int hw = h0p[(size_t)s * NN1 * 16 + (size_t)nc * 16 + d];  // hoisted
    float di = dinv[nc];
    int base = ns << 4;
    float a0 = 0.f, a1 = 0.f;
    int p = p0;
    while (p < p1) {                      // group-uniform trip count
        int rem = p1 - p;                 // multiple of 8
        int jv = (int)col[p + d];         // 16 edge ids (slack-safe at array end)
        {
            int j0 = __shfl(jv, base + 0), j1 = __shfl(jv, base + 1);
            int j2 = __shfl(jv, base + 2), j3 = __shfl(jv, base + 3);
            int j4 = __shfl(jv, base + 4), j5 = __shfl(jv, base + 5);
            int j6 = __shfl(jv, base + 6), j7 = __shfl(jv, base + 7);
            unsigned int w0 = hsq[j0 * 16 + d], w1 = hsq[j1 * 16 + d];
            unsigned int w2 = hsq[j2 * 16 + d], w3 = hsq[j3 * 16 + d];
            unsigned int w4 = hsq[j4 * 16 + d], w5 = hsq[j5 * 16 + d];
            unsigned int w6 = hsq[j6 * 16 + d], w7 = hsq[j7 * 16 + d];
            a0 += lo16(w0) + lo16(w1) + lo16(w2) + lo16(w3) +
                  lo16(w4) + lo16(w5) + lo16(w6) + lo16(w7);
            a1 += hi16(w0) + hi16(w1) + hi16(w2) + hi16(w3) +
                  hi16(w4) + hi16(w5) + hi16(w6) + hi16(w7);
        }
        if (rem > 8) {
            int j0 = __shfl(jv, base + 8),  j1 = __shfl(jv, base + 9);
            int j2 = __shfl(jv, base + 10), j3 = __shfl(jv, base + 11);
            int j4 = __shfl(jv, base + 12), j5 = __shfl(jv, base + 13);
            int j6 = __shfl(jv, base + 14), j7 = __shfl(jv, base + 15);
            unsigned int w0 = hsq[j0 * 16 + d], w1 = hsq[j1 * 16 + d];
            unsigned int w2 = hsq[j2 * 16 + d], w3 = hsq[j3 * 16 + d];
            unsigned int w4 = hsq[j4 * 16 + d], w5 = hsq[j5 * 16 + d];
            unsigned int w6 = hsq[j6 * 16 + d], w7 = hsq[j7 * 16 + d];
            a0 += lo16(w0) + lo16(w1) + lo16(w2) + lo16(w3) +
                  lo16(w4) + lo16(w5) + lo16(w6) + lo16(w7);
            a1 += hi16(w0) + hi16(w1) + hi16(w2) + hi16(w3) +
                  hi16(w4) + hi16(w5) + hi16(w6) + hi16(w7);
        }
        p += 16;
    }
    float n0 = 0.9f * di * a0 + 0.1f * lo16(hw);
    float n1 = 0.9f * di * a1 + 0.1f * hi16(hw);
    if (valid) {
        if (!writeOut) {
            hs_out[(size_t)s * NN1 * 16 + (size_t)n * 16 + d] = pack2(di * n0, di * n1);
        } else {
            size_t obase = (size_t)n * 129 + s * 32 + 2 * d;
            if (*flag) {
                float* o = (float*)out;
                o[obase] = n0;
                o[obase + 1] = n1;
                if (s == 0 && d == 0) o[(size_t)n * 129 + 128] = Jf[n];
            } else {
                ushort_t* o = (ushort_t*)out;
                o[obase] = f2bf(n0);
                o[obase + 1] = f2bf(n1);
                if (s == 0 && d == 0) o[(size_t)n * 129 + 128] = f2bf(Jf[n]);
            }
        }
    }
}

// ---------------- 64x128-tile MFMA GEMM, double-buffered ----------
// MODE 3: outB = bf16(acc)   (used for xl = h @ gat_w)
template <int MODE>
__global__ __launch_bounds__(256) void k_gemm64(const ushort_t* __restrict__ A,
                                                const ushort_t* __restrict__ Bt,
                                                int M, int K, int Nc,
                                                const float* __restrict__ bias,
                                                const ushort_t* __restrict__ res,
                                                ushort_t* __restrict__ outB,
                                                float* __restrict__ stats) {
    __shared__ __align__(16) ushort_t lsA[2][64 * 32];
    __shared__ __align__(16) ushort_t lsB[2][128 * 32];
    int t = threadIdx.x;
    int m0 = blockIdx.x * 64;
    int n0 = blockIdx.y * 128;
    int w = t >> 6, lane = t & 63;
    int row16 = lane & 15, quad = lane >> 4;
    int nbase = w * 32;
    float4_t acc[8];
#pragma unroll
    for (int i = 0; i < 8; ++i) acc[i] = (float4_t){0.f, 0.f, 0.f, 0.f};
    int lrow = lane >> 2;
    int lcol = (lane & 3) * 8;
    const ushort_t* gA  = A  + (size_t)(m0 + w * 16 + lrow) * K + lcol;
    const ushort_t* gB0 = Bt + (size_t)(n0 + w * 32 + lrow) * K + lcol;
    const ushort_t* gB1 = Bt + (size_t)(n0 + w * 32 + 16 + lrow) * K + lcol;
    ushort_t* dA  = &lsA[0][0] + (w * 16) * 32;
    ushort_t* dB0 = &lsB[0][0] + (w * 32) * 32;
    ushort_t* dB1 = &lsB[0][0] + (w * 32 + 16) * 32;
    const int bufStrideA = 64 * 32, bufStrideB = 128 * 32;
    const int nK = K >> 5;
    gl_lds16(gA, dA);
    gl_lds16(gB0, dB0);
    gl_lds16(gB1, dB1);
    for (int kb = 0; kb < nK; ++kb) {
        __syncthreads();
        int nb = kb + 1;
        if (nb < nK) {
            int b = nb & 1;
            int k0 = nb << 5;
            gl_lds16(gA + k0, dA + b * bufStrideA);
            gl_lds16(gB0 + k0, dB0 + b * bufStrideB);
            gl_lds16(gB1 + k0, dB1 + b * bufStrideB);
        }
        const ushort_t* la = &lsA[kb & 1][0];
        const ushort_t* lb = &lsB[kb & 1][0];
        short8_t afr[4], bfr[2];
#pragma unroll
        for (int i = 0; i < 4; ++i)
            afr[i] = *(const short8_t*)(la + (i * 16 + row16) * 32 + quad * 8);
#pragma unroll
        for (int i = 0; i < 2; ++i)
            bfr[i] = *(const short8_t*)(lb + (nbase + i * 16 + row16) * 32 + quad * 8);
#pragma unroll
        for (int mt = 0; mt < 4; ++mt)
#pragma unroll
            for (int nt = 0; nt < 2; ++nt)
                acc[mt * 2 + nt] = __builtin_amdgcn_mfma_f32_16x16x32_bf16(
                    afr[mt], bfr[nt], acc[mt * 2 + nt], 0, 0, 0);
    }
#pragma unroll
    for (int mt = 0; mt < 4; ++mt) {
#pragma unroll
        for (int nt = 0; nt < 2; ++nt) {
            int cc = n0 + nbase + nt * 16 + row16;
#pragma unroll
            for (int r = 0; r < 4; ++r) {
                int rr = m0 + mt * 16 + quad * 4 + r;
                if (rr < M) {
                    outB[(size_t)rr * Nc + cc] = f2bf(acc[mt * 2 + nt][r]);
                }
            }
        }
    }
}

// ---------------- fused FFN (BM=64): z = relu(A@W2+b2)@W3 + b3 + res ----
// A:[NP][128] bf16, W2t:[512 n][128 k] bf16, W3t:[128 n][512 k, sigma-permuted].
// LDS = 16K(W2) + 16K(W3) + 16K(A prologue -> H 8K + stats 1K) = 48KB -> 3
// blocks/CU. Waves 2m x 2n; afrA hoisted (32 VGPRs). Two barriers per chunk
// with staggered single-buffer restaging. Verified 57us; BM=32 regressed
// (staging traffic doubles with block count).
__global__ __launch_bounds__(256, 3) void k_ffn(const ushort_t* __restrict__ A,
                                                const ushort_t* __restrict__ W2t,
                                                const ushort_t* __restrict__ W3t,
                                                const float* __restrict__ b2,
                                                const float* __restrict__ b3,
                                                const ushort_t* __restrict__ res,
                                                ushort_t* __restrict__ outB,
                                                float* __restrict__ stats) {
    __shared__ __align__(16) ushort_t sW2[4 * 64 * 32];   // 16KB [kb][64 n][32 k]
    __shared__ __align__(16) ushort_t sW3[2 * 128 * 32];  // 16KB [ks][128 n][32 k]
    __shared__ __align__(16) ushort_t sAH[4 * 2048];      // 16KB A prologue; then H+stats
    int t = threadIdx.x;
    int w = t >> 6, lane = t & 63;
    int wm = w >> 1, wn = w & 1;
    int m0 = blockIdx.x * 64;
    int row16 = lane & 15, quad = lane >> 4;
    int sw = (row16 >> 2) & 3;   // read-side k-group swizzle
    int srow = lane >> 2;        // staging: row within a 16-row issue
    int klin = lane & 3;         // staging: linear k-group this lane fills

    // ---- prologue staging: A tile, W2 chunk 0, W3 chunk 0 ----
#pragma unroll
    for (int i = 0; i < 4; ++i) {
        int row = i * 16 + srow;
        int kc = klin ^ ((row >> 2) & 3);
        gl_lds16(A + (size_t)(m0 + row) * 128 + w * 32 + kc * 8,
                 sAH + w * 2048 + i * 512);
        gl_lds16(W2t + (size_t)row * 128 + w * 32 + kc * 8,
                 sW2 + w * 2048 + i * 512);
        int f = w * 4 + i;
        int ks = f >> 3;
        int n3 = (f & 7) * 16 + srow;
        int kc3 = klin ^ ((n3 >> 2) & 3);
        gl_lds16(W3t + (size_t)n3 * 512 + ks * 32 + kc3 * 8,
                 sW3 + f * 512);
    }
    __syncthreads();

    // hoist A fragments (chunk-invariant): afrA[mt][kb], 32 VGPRs
    short8_t afrA[2][4];
#pragma unroll
    for (int mt = 0; mt < 2; ++mt)
#pragma unroll
        for (int kb = 0; kb < 4; ++kb)
            afrA[mt][kb] = *(const short8_t*)(sAH + kb * 2048 +
                                              (wm * 32 + mt * 16 + row16) * 32 + (quad ^ sw) * 8);
    __syncthreads();   // A region free -> H + stats

    char* Hb = (char*)sAH;             // 8KB H: 64 rows x 128B
    float* s1 = (float*)(Hb + 8192);   // 128 f32
    float* s2 = s1 + 128;
    if (t < 128) { s1[t] = 0.f; s2[t] = 0.f; }

    float4_t accz[2][4];
#pragma unroll
    for (int mt = 0; mt < 2; ++mt)
#pragma unroll
        for (int nt = 0; nt < 4; ++nt) accz[mt][nt] = (float4_t){0.f, 0.f, 0.f, 0.f};

    for (int c = 0; c < 8; ++c) {
        // ---- phase 1: hid_c = relu(A @ W2[:, 64c:64c+64] + b2), n-slice wn ----
        float b20 = b2[c * 64 + wn * 32 + row16];
        float b21 = b2[c * 64 + wn * 32 + 16 + row16];
        float4_t acch[2][2];
#pragma unroll
        for (int mt = 0; mt < 2; ++mt)
#pragma unroll
            for (int nt = 0; nt < 2; ++nt) acch[mt][nt] = (float4_t){0.f, 0.f, 0.f, 0.f};
#pragma unroll
        for (int kb = 0; kb < 4; ++kb) {
            short8_t b0 = *(const short8_t*)(sW2 + kb * 2048 +
                                             (wn * 32 + row16) * 32 + (quad ^ sw) * 8);
            short8_t b1 = *(const short8_t*)(sW2 + kb * 2048 +
                                             (wn * 32 + 16 + row16) * 32 + (quad ^ sw) * 8);
            acch[0][0] = __builtin_amdgcn_mfma_f32_16x16x32_bf16(afrA[0][kb], b0, acch[0][0], 0, 0, 0);
            acch[0][1] = __builtin_amdgcn_mfma_f32_16x16x32_bf16(afrA[0][kb], b1, acch[0][1], 0, 0, 0);
            acch[1][0] = __builtin_amdgcn_mfma_f32_16x16x32_bf16(afrA[1][kb], b0, acch[1][0], 0, 0, 0);
            acch[1][1] = __builtin_amdgcn_mfma_f32_16x16x32_bf16(afrA[1][kb], b1, acch[1][1], 0, 0, 0);
        }
        // relu+bias -> packed H writes (8 x b32 per lane, 2-way banks = free)
#pragma unroll
        for (int mt = 0; mt < 2; ++mt) {
#pragma unroll
            for (int r = 0; r < 4; ++r) {
                int row = wm * 32 + mt * 16 + quad * 4 + r;
                int d = wn * 16 + row16;
                int byteOff = row * 128 + ((((d >> 2) ^ (row & 7))) << 4) + (d & 3) * 4;
                float v0 = acch[mt][0][r] + b20; v0 = v0 > 0.f ? v0 : 0.f;
                float v1 = acch[mt][1][r] + b21; v1 = v1 > 0.f ? v1 : 0.f;
                *(unsigned int*)(Hb + byteOff) = pack2(v0, v1);
            }
        }
        __syncthreads();   // B1: H visible to all waves; W2(c) fully consumed
        if (c < 7) {       // restage W2 (drained by vmcnt(0) at B2)
#pragma unroll
            for (int i = 0; i < 4; ++i) {
                int n = i * 16 + srow;
                int kc = klin ^ ((n >> 2) & 3);
                gl_lds16(W2t + (size_t)((c + 1) * 64 + n) * 128 + w * 32 + kc * 8,
                         sW2 + w * 2048 + i * 512);
            }
        }
        // ---- phase 2: accz += hid_c @ W3[64c:64c+64, :], n-half wn ----
#pragma unroll
        for (int ks = 0; ks < 2; ++ks) {
            short8_t afrH[2];
#pragma unroll
            for (int mt = 0; mt < 2; ++mt)
                afrH[mt] = *(const short8_t*)(Hb + (wm * 32 + mt * 16 + row16) * 128 +
                                              (((ks * 4 + quad) ^ (row16 & 7)) << 4));
#pragma unroll
            for (int nt = 0; nt < 4; ++nt) {
                short8_t bfr = *(const short8_t*)(sW3 + ks * 4096 +
                                                  (wn * 64 + nt * 16 + row16) * 32 + (quad ^ sw) * 8);
                accz[0][nt] = __builtin_amdgcn_mfma_f32_16x16x32_bf16(afrH[0], bfr, accz[0][nt], 0, 0, 0);
                accz[1][nt] = __builtin_amdgcn_mfma_f32_16x16x32_bf16(afrH[1], bfr, accz[1][nt], 0, 0, 0);
            }
        }
        __syncthreads();   // B2: W3(c)+H consumed; W2(c+1) drained here
        if (c < 7) {       // restage W3 (drained by vmcnt(0) at next B1)
#pragma unroll
            for (int i = 0; i < 4; ++i) {
                int f = w * 4 + i;
                int ks = f >> 3;
                int n = (f & 7) * 16 + srow;
                int kc = klin ^ ((n >> 2) & 3);
                gl_lds16(W3t + (size_t)n * 512 + (c + 1) * 64 + ks * 32 + kc * 8,
                         sW3 + f * 512);
            }
        }
    }

    // ---- epilogue: z = accz + b3 + res ; write bf16 + BN stats ----
#pragma unroll
    for (int mt = 0; mt < 2; ++mt) {
#pragma unroll
        for (int nt = 0; nt < 4; ++nt) {
            int cc = wn * 64 + nt * 16 + row16;
            float bv = b3[cc];
            float ls = 0.f, lq = 0.f;
#pragma unroll
            for (int r = 0; r < 4; ++r) {
                int rr = m0 + wm * 32 + mt * 16 + quad * 4 + r;
                if (rr < NN) {
                    float v = accz[mt][nt][r] + bv + bf2f(res[(size_t)rr * 128 + cc]);
                    outB[(size_t)rr * 128 + cc] = f2bf(v);
                    ls += v;
                    lq += v * v;
                }
            }
            atomicAdd(&s1[cc], ls);
            atomicAdd(&s2[cc], lq);
        }
    }
    __syncthreads();
    if (t < 128) {
        atomicAdd(&stats[t], s1[t]);
        atomicAdd(&stats[128 + t], s2[t]);
    }
}

// ---------------- host ----------------
extern "C" void kernel_launch(void* const* d_in, const int* in_sizes, int n_in,
                              void* d_out, int out_size, void* d_ws, size_t ws_size,
                              hipStream_t stream) {
    const int* ei = (const int*)d_in[2];

    char* p = (char*)d_ws;
    auto alloc = [&](size_t bytes) {
        void* r = (void*)p;
        p += (bytes + 255) & ~(size_t)255;
        return r;
    };
    ushort_t* hB    = (ushort_t*)alloc((size_t)NP * DEMB * 2);   // h (padded)
    ushort_t* h1B   = (ushort_t*)alloc((size_t)NP * DEMB * 2);   // h1 (padded)
    ushort_t* xlB   = (ushort_t*)alloc((size_t)NN * DEMB * 2);   // xl, reused as zB
    unsigned int* hsA  = (unsigned int*)alloc((size_t)4 * NN1 * 16 * 4);
    unsigned int* hsB_ = (unsigned int*)alloc((size_t)4 * NN1 * 16 * 4);
    unsigned int* h0p  = (unsigned int*)alloc((size_t)4 * NN1 * 16 * 4);
    float*    asv   = (float*)alloc((size_t)NN * 8 * 4);
    float*    adv   = (float*)alloc((size_t)NN * 8 * 4);
    float*    gv    = (float*)alloc((size_t)NN * 16 * 4);
    float*    dinvv = (float*)alloc((size_t)NN * 4);
    float*    stats = (float*)alloc(4 * 256 * 4);
    int*      deg   = (int*)alloc((size_t)NN * 4);
    int*      rowp  = (int*)alloc((size_t)(NN + 1) * 4);
    int*      fill  = (int*)alloc((size_t)NN * 4);
    ushort_t* colv  = (ushort_t*)alloc((size_t)EPP_MAX * 2);
    int*      part  = (int*)alloc(NB_SCAN * 4);
    int*      poff  = (int*)alloc(NB_SCAN * 4);
    int*      flag  = (int*)alloc(256);
    ushort_t* wtg   = (ushort_t*)alloc((size_t)2 * 128 * 128 * 2);
    ushort_t* wt2   = (ushort_t*)alloc((size_t)2 * 512 * 128 * 2);
    ushort_t* wt3   = (ushort_t*)alloc((size_t)2 * 128 * 512 * 2);
    float* xf   = (float*)alloc((size_t)NN * 2 * 4);
    float* Jf   = (float*)alloc((size_t)NN * 4);
    float* l0wF = (float*)alloc(384 * 4);
    float* l0bF = (float*)alloc(128 * 4);
    float* gwF  = (float*)alloc(32768 * 4);
    float* asF  = (float*)alloc(256 * 4);
    float* adF  = (float*)alloc(256 * 4);
    float* w1F  = (float*)alloc(4096 * 4);
    float* b1gF = (float*)alloc(256 * 4);
    float* b1bF = (float*)alloc(256 * 4);
    float* w2F  = (float*)alloc(131072 * 4);
    float* b2F  = (float*)alloc(1024 * 4);
    float* w3F  = (float*)alloc(131072 * 4);
    float* b3F  = (float*)alloc(256 * 4);
    float* b2gF = (float*)alloc(256 * 4);
    float* b2bF = (float*)alloc(256 * 4);

    // ---- dtype detect + batched canonicalize ----
    k_detect<<<1, 64, 0, stream>>>((const unsigned int*)d_in[1], flag);
    CvtArgs ca;
    {
        const int srcIdx[16] = {0, 1, 3, 4, 5, 6, 7, 8, 9, 10, 11, 12, 13, 14, 15, 16};
        float* dsts[16] = {xf, Jf, l0wF, l0bF, gwF, asF, adF, w1F, b1gF, b1bF,
                           w2F, b2F, w3F, b3F, b2gF, b2bF};
        const int ns[16] = {NN * 2, NN, 384, 128, 32768, 256, 256, 4096, 256, 256,
                            131072, 1024, 131072, 256, 256, 256};
        for (int i = 0; i < 16; ++i) { ca.src[i] = d_in[srcIdx[i]]; ca.dst[i] = dsts[i]; ca.n[i] = ns[i]; }
    }
    k_cvt_all<<<dim3(cdiv(131072, 256), 16), 256, 0, stream>>>(ca, flag);

    // ---- CSR build (padded rows) ----
    hipMemsetAsync(deg, 0, (size_t)NN * 4, stream);
    hipMemsetAsync(stats, 0, 4 * 256 * 4, stream);
    k_deg<<<cdiv(EP, 256), 256, 0, stream>>>(ei, deg);
    k_part<<<NB_SCAN, 256, 0, stream>>>(deg, part);
    k_scan2<<<1, 256, 0, stream>>>(part, poff, rowp);
    k_rowp<<<NB_SCAN, 256, 0, stream>>>(deg, poff, rowp, dinvv, fill);
    k_fill<<<cdiv(EP, 256), 256, 0, stream>>>(ei, fill, colv);
    k_pad<<<cdiv(NN, 256), 256, 0, stream>>>(fill, rowp, colv);
    k_zsent<<<1, 64, 0, stream>>>(hsA, hsB_);

    // ---- batched weight transposes (W3 gets the sigma k-perm for BM=64 ffn) ----
    TrArgs ta;
    {
        const float* srcs[6] = {gwF, gwF + 16384, w2F, w2F + 65536, w3F, w3F + 65536};
        ushort_t* dsts[6] = {wtg, wtg + 16384, wt2, wt2 + 65536, wt3, wt3 + 65536};
        const int Ks[6] = {128, 128, 128, 128, 512, 512};
        const int Ncs[6] = {128, 128, 512, 512, 128, 128};
        const int perms[6] = {0, 0, 0, 0, 1, 1};
        for (int i = 0; i < 6; ++i) {
            ta.src[i] = srcs[i]; ta.dst[i] = dsts[i]; ta.K[i] = Ks[i]; ta.Nc[i] = Ncs[i];
            ta.perm[i] = perms[i];
        }
    }
    k_tr_all<<<dim3(cdiv(65536, 256), 6), 256, 0, stream>>>(ta);

    // ---- input projection (bf16 h only) ----
    k_lin0<<<cdiv(NN * DEMB, 256), 256, 0, stream>>>(xf, Jf, l0wF, l0bF, hB);

    for (int l = 0; l < 2; ++l) {
        float* st1 = stats + (l * 2 + 0) * 256;
        float* st2 = stats + (l * 2 + 1) * 256;
        ushort_t* zB = xlB;  // reuse xl buffer for z after k_gat is done
        // xl (bf16) = h @ gat_w[l]
        k_gemm64<3><<<dim3(NMT64, 1), 256, 0, stream>>>(hB, wtg + l * 16384, NN, 128, 128,
                                                        nullptr, nullptr, xlB, nullptr);
        k_att<<<cdiv(NN * 8, 256), 256, 0, stream>>>((const unsigned int*)xlB, asF + l * 128,
                                                     adF + l * 128, asv, adv);
        k_gat<<<cdiv(NN * 64, 256), 256, 0, stream>>>(rowp, deg, colv, asv, adv,
                                                      (const unsigned int*)xlB, gv);
        k_z1s<<<512, 256, 0, stream>>>(hB, gv, w1F + l * 2048, st1);
        k_bnapply1<<<cdiv(NN * DEMB, 256), 256, 0, stream>>>(hB, gv, w1F + l * 2048, st1,
                                                             b1gF + l * 128, b1bF + l * 128,
                                                             h1B);
        // fused FFN: z = relu(h1@W2+b2)@W3 + b3 + h1, + BN2 stats
        k_ffn<<<NMT64, 256, 0, stream>>>(h1B, wt2 + l * 65536, wt3 + l * 65536,
                                         b2F + l * 512, b3F + l * 128, h1B, zB, st2);
        if (l == 0) {
            k_bnapply<<<cdiv(NN * DEMB, 256), 256, 0, stream>>>(zB, st2, b2gF, b2bF, hB);
        } else {
            k_bnapply_fin<<<cdiv(NN * 64, 256), 256, 0, stream>>>((const unsigned int*)zB, st2,
                                                                  b2gF + 128, b2bF + 128,
                                                                  dinvv, hsA, h0p);
        }
    }

    // ---- APPNP: 10 steps (slabbed, 4 nodes/wave, predication-free); last writes d_out ----
    unsigned int* pin = hsA;
    unsigned int* pout = hsB_;
    for (int k = 0; k < 10; ++k) {
        int last = (k == 9) ? 1 : 0;
        k_appnp<<<12504, 256, 0, stream>>>(rowp, colv, dinvv, pin, h0p, pout,
                                           Jf, flag, d_out, last);
        unsigned int* tmp = pout;
        pout = pin;
        pin = tmp;
    }
}